// Round 2
// baseline (1550.540 us; speedup 1.0000x reference)
//
#include <hip/hip_runtime.h>
#include <hip/hip_bf16.h>

#define NN 50000
#define NE 800000
#define NF 128
#define HH 96
#define TF 10
#define Z1DIM (HH + TF)   // 106
#define Z2DIM (HH + NF)   // 224

// ---- kernel 1: deg = 1 (self loop) ----
__global__ void k_init_deg(float* __restrict__ deg) {
    int i = blockIdx.x * 256 + threadIdx.x;
    if (i < NN) deg[i] = 1.0f;
}

// ---- kernel 2: deg[dst] += 1 over real edges ----
__global__ void k_count(const int* __restrict__ dst, float* __restrict__ deg) {
    int e = blockIdx.x * 256 + threadIdx.x;
    if (e < NE) unsafeAtomicAdd(&deg[dst[e]], 1.0f);
}

// ---- kernel 3: h' = (x @ W_gcn) * rsqrt(deg[row]); acc = h' (self-loop term) ----
__global__ void k_gemm1(const float* __restrict__ x,
                        const float* __restrict__ W,
                        const float* __restrict__ deg,
                        float* __restrict__ hp, float* __restrict__ acc) {
    int t = blockIdx.x * 256 + threadIdx.x;
    if (t >= NN * HH) return;
    int i = t / HH;
    int j = t - i * HH;
    const float4* xr = (const float4*)(x + (size_t)i * NF);
    float s = 0.f;
#pragma unroll
    for (int k4 = 0; k4 < NF / 4; ++k4) {
        float4 xv = xr[k4];
        int k = k4 * 4;
        s = fmaf(xv.x, W[(k + 0) * HH + j], s);
        s = fmaf(xv.y, W[(k + 1) * HH + j], s);
        s = fmaf(xv.z, W[(k + 2) * HH + j], s);
        s = fmaf(xv.w, W[(k + 3) * HH + j], s);
    }
    float v = s * rsqrtf(deg[i]);
    hp[t] = v;
    acc[t] = v;
}

// ---- kernel 4: acc[dst] += h'[src] over edges. 24 lanes/edge, 4 floats each ----
__global__ void k_scatter(const int* __restrict__ ei,
                          const float* __restrict__ hp,
                          float* __restrict__ acc) {
    int t = blockIdx.x * 256 + threadIdx.x;
    int e = t / 24;
    if (e >= NE) return;
    int q = (t - e * 24) * 4;
    int s = ei[e];
    int d = ei[NE + e];
    const float4 v = *(const float4*)(hp + (size_t)s * HH + q);
    float* a = acc + (size_t)d * HH + q;
    unsafeAtomicAdd(a + 0, v.x);
    unsafeAtomicAdd(a + 1, v.y);
    unsafeAtomicAdd(a + 2, v.z);
    unsafeAtomicAdd(a + 3, v.w);
}

// ---- kernel 5: fused epilogue per node ----
// g = relu(dinv*acc + b_gcn); z=[g,temporal]; a1=relu(z@W1+b1); z2=[a1,x]; out=relu(z2@W2+b2)
#define NPB 8
__global__ __launch_bounds__(128) void k_mlp(
    const float* __restrict__ acc, const float* __restrict__ deg,
    const float* __restrict__ x, const float* __restrict__ tmp,
    const float* __restrict__ bg, const float* __restrict__ W1,
    const float* __restrict__ b1, const float* __restrict__ W2,
    const float* __restrict__ b2, float* __restrict__ out) {
    __shared__ float sW1[Z1DIM * HH];  // 40704 B
    __shared__ float sW2[Z2DIM];
    __shared__ float sb1[HH], sbg[HH];
    __shared__ float sz[Z1DIM];
    __shared__ float sa[HH];
    __shared__ float sred[2];
    const int t = threadIdx.x;

    for (int m = t; m < Z1DIM * HH; m += 128) sW1[m] = W1[m];
    for (int m = t; m < Z2DIM; m += 128) sW2[m] = W2[m];
    if (t < HH) { sb1[t] = b1[t]; sbg[t] = bg[t]; }
    __syncthreads();
    const float bias2 = b2[0];

    const int base = blockIdx.x * NPB;
    for (int n = 0; n < NPB; ++n) {
        int i = base + n;
        if (i >= NN) return;  // uniform across block (never taken with exact grid)
        float dinv = rsqrtf(deg[i]);
        if (t < HH)
            sz[t] = fmaxf(fmaf(dinv, acc[(size_t)i * HH + t], sbg[t]), 0.f);
        else if (t < Z1DIM)
            sz[t] = tmp[(size_t)i * TF + (t - HH)];
        __syncthreads();
        if (t < HH) {
            float s1 = sb1[t];
#pragma unroll 2
            for (int k = 0; k < Z1DIM; ++k)
                s1 = fmaf(sz[k], sW1[k * HH + t], s1);
            sa[t] = fmaxf(s1, 0.f);
        }
        __syncthreads();
        float p = 0.f;
        for (int k = t; k < Z2DIM; k += 128) {
            float zv = (k < HH) ? sa[k] : x[(size_t)i * NF + (k - HH)];
            p = fmaf(zv, sW2[k], p);
        }
#pragma unroll
        for (int off = 32; off > 0; off >>= 1) p += __shfl_down(p, off, 64);
        if ((t & 63) == 0) sred[t >> 6] = p;
        __syncthreads();
        if (t == 0)
            out[i] = fmaxf(sred[0] + sred[1] + bias2, 0.f);
        __syncthreads();
    }
}

extern "C" void kernel_launch(void* const* d_in, const int* in_sizes, int n_in,
                              void* d_out, int out_size, void* d_ws, size_t ws_size,
                              hipStream_t stream) {
    const float* x   = (const float*)d_in[0];
    const int*   ei  = (const int*)d_in[1];
    const float* tmp = (const float*)d_in[2];
    const float* Wg  = (const float*)d_in[3];
    const float* bg  = (const float*)d_in[4];
    const float* W1  = (const float*)d_in[5];
    const float* b1  = (const float*)d_in[6];
    const float* W2  = (const float*)d_in[7];
    const float* b2  = (const float*)d_in[8];
    float* out = (float*)d_out;

    float* ws  = (float*)d_ws;
    float* deg = ws;                      // N floats (padded to 65536)
    float* hp  = ws + 65536;              // N*96 floats
    float* acc = hp + (size_t)NN * HH;    // N*96 floats  (total ~38.7 MB)

    k_init_deg<<<(NN + 255) / 256, 256, 0, stream>>>(deg);
    k_count<<<(NE + 255) / 256, 256, 0, stream>>>(ei + NE, deg);
    k_gemm1<<<(NN * HH + 255) / 256, 256, 0, stream>>>(x, Wg, deg, hp, acc);
    k_scatter<<<((NE * 24) + 255) / 256, 256, 0, stream>>>(ei, hp, acc);
    k_mlp<<<(NN + NPB - 1) / NPB, 128, 0, stream>>>(acc, deg, x, tmp, bg, W1, b1, W2, b2, out);
}

// Round 3
// 834.894 us; speedup vs baseline: 1.8572x; 1.8572x over previous
//
#include <hip/hip_runtime.h>
#include <hip/hip_bf16.h>

#define NN 50000
#define NE 800000
#define NF 128
#define HH 96
#define TF 10
#define Z1DIM (HH + TF)   // 106
#define Z2DIM (HH + NF)   // 224

// ---- kernel 1: zero cnt & cur ----
__global__ void k_zero(int* __restrict__ cnt, int* __restrict__ cur) {
    int i = blockIdx.x * 256 + threadIdx.x;
    if (i < NN) { cnt[i] = 0; cur[i] = 0; }
}

// ---- kernel 2: cnt[dst]++ over real edges ----
__global__ void k_count(const int* __restrict__ dst, int* __restrict__ cnt) {
    int e = blockIdx.x * 256 + threadIdx.x;
    if (e < NE) atomicAdd(&cnt[dst[e]], 1);
}

// ---- kernel 3: exclusive scan of cnt -> off (single block, 1024 threads) ----
#define SCANT 1024
#define CHUNK ((NN + SCANT - 1) / SCANT)   // 49
__global__ __launch_bounds__(SCANT) void k_scan(const int* __restrict__ cnt,
                                                int* __restrict__ off) {
    __shared__ int partial[SCANT];
    const int t = threadIdx.x;
    const int lo = t * CHUNK;
    const int hi = min(lo + CHUNK, NN);
    int s = 0;
    for (int i = lo; i < hi; ++i) s += cnt[i];
    partial[t] = s;
    __syncthreads();
    // inclusive Hillis-Steele scan over 1024 partials
    for (int d = 1; d < SCANT; d <<= 1) {
        int v = (t >= d) ? partial[t - d] : 0;
        __syncthreads();
        partial[t] += v;
        __syncthreads();
    }
    int base = (t > 0) ? partial[t - 1] : 0;
    for (int i = lo; i < hi; ++i) { off[i] = base; base += cnt[i]; }
    if (t == SCANT - 1) off[NN] = base;
}

// ---- kernel 4: scatter edge src ids into CSR slots ----
__global__ void k_fill(const int* __restrict__ ei, const int* __restrict__ off,
                       int* __restrict__ cur, int* __restrict__ csr) {
    int e = blockIdx.x * 256 + threadIdx.x;
    if (e >= NE) return;
    int s = ei[e];
    int d = ei[NE + e];
    int slot = off[d] + atomicAdd(&cur[d], 1);
    csr[slot] = s;
}

// ---- kernel 5: hp = (x @ W_gcn) * rsqrt(deg_total[row]) ----
__global__ void k_gemm1(const float* __restrict__ x,
                        const float* __restrict__ W,
                        const int* __restrict__ cnt,
                        float* __restrict__ hp) {
    int t = blockIdx.x * 256 + threadIdx.x;
    if (t >= NN * HH) return;
    int i = t / HH;
    int j = t - i * HH;
    const float4* xr = (const float4*)(x + (size_t)i * NF);
    float s = 0.f;
#pragma unroll
    for (int k4 = 0; k4 < NF / 4; ++k4) {
        float4 xv = xr[k4];
        int k = k4 * 4;
        s = fmaf(xv.x, W[(k + 0) * HH + j], s);
        s = fmaf(xv.y, W[(k + 1) * HH + j], s);
        s = fmaf(xv.z, W[(k + 2) * HH + j], s);
        s = fmaf(xv.w, W[(k + 3) * HH + j], s);
    }
    hp[t] = s * rsqrtf((float)cnt[i] + 1.0f);
}

// ---- kernel 6: fused aggregation + MLP epilogue per node ----
// agg_j = hp[i][j] + sum_{e in-edges} hp[src_e][j]
// g = relu(dinv*agg + b_gcn); z=[g,temporal]; a1=relu(z@W1+b1); out=relu([a1,x]@W2+b2)
#define NPB 8
__global__ __launch_bounds__(128) void k_mlp(
    const float* __restrict__ hp, const int* __restrict__ cnt,
    const int* __restrict__ off, const int* __restrict__ csr,
    const float* __restrict__ x, const float* __restrict__ tmp,
    const float* __restrict__ bg, const float* __restrict__ W1,
    const float* __restrict__ b1, const float* __restrict__ W2,
    const float* __restrict__ b2, float* __restrict__ out) {
    __shared__ float sW1[Z1DIM * HH];  // 40704 B
    __shared__ float sW2[Z2DIM];
    __shared__ float sb1[HH], sbg[HH];
    __shared__ float sz[Z1DIM];
    __shared__ float sa[HH];
    __shared__ float sred[2];
    const int t = threadIdx.x;

    for (int m = t; m < Z1DIM * HH; m += 128) sW1[m] = W1[m];
    for (int m = t; m < Z2DIM; m += 128) sW2[m] = W2[m];
    if (t < HH) { sb1[t] = b1[t]; sbg[t] = bg[t]; }
    __syncthreads();
    const float bias2 = b2[0];

    const int base = blockIdx.x * NPB;
    for (int n = 0; n < NPB; ++n) {
        int i = base + n;
        if (i >= NN) return;  // uniform across block
        float dinv = rsqrtf((float)cnt[i] + 1.0f);
        if (t < HH) {
            // gather-aggregate incoming messages (no atomics)
            float s = hp[(size_t)i * HH + t];   // self-loop term
            int idx = off[i];
            const int end = idx + cnt[i];
            for (; idx + 1 < end; idx += 2) {
                int s0 = csr[idx], s1 = csr[idx + 1];
                s += hp[(size_t)s0 * HH + t];
                s += hp[(size_t)s1 * HH + t];
            }
            if (idx < end) s += hp[(size_t)csr[idx] * HH + t];
            sz[t] = fmaxf(fmaf(dinv, s, sbg[t]), 0.f);
        } else if (t < Z1DIM) {
            sz[t] = tmp[(size_t)i * TF + (t - HH)];
        }
        __syncthreads();
        if (t < HH) {
            float s1 = sb1[t];
#pragma unroll 2
            for (int k = 0; k < Z1DIM; ++k)
                s1 = fmaf(sz[k], sW1[k * HH + t], s1);
            sa[t] = fmaxf(s1, 0.f);
        }
        __syncthreads();
        float p = 0.f;
        for (int k = t; k < Z2DIM; k += 128) {
            float zv = (k < HH) ? sa[k] : x[(size_t)i * NF + (k - HH)];
            p = fmaf(zv, sW2[k], p);
        }
#pragma unroll
        for (int o = 32; o > 0; o >>= 1) p += __shfl_down(p, o, 64);
        if ((t & 63) == 0) sred[t >> 6] = p;
        __syncthreads();
        if (t == 0)
            out[i] = fmaxf(sred[0] + sred[1] + bias2, 0.f);
        __syncthreads();
    }
}

extern "C" void kernel_launch(void* const* d_in, const int* in_sizes, int n_in,
                              void* d_out, int out_size, void* d_ws, size_t ws_size,
                              hipStream_t stream) {
    const float* x   = (const float*)d_in[0];
    const int*   ei  = (const int*)d_in[1];
    const float* tmp = (const float*)d_in[2];
    const float* Wg  = (const float*)d_in[3];
    const float* bg  = (const float*)d_in[4];
    const float* W1  = (const float*)d_in[5];
    const float* b1  = (const float*)d_in[6];
    const float* W2  = (const float*)d_in[7];
    const float* b2  = (const float*)d_in[8];
    float* out = (float*)d_out;

    int* cnt = (int*)d_ws;           // NN (padded 65536)
    int* cur = cnt + 65536;          // NN
    int* off = cur + 65536;          // NN+1
    int* csr = off + 65536;          // NE (800000)
    float* hp = (float*)(((char*)d_ws) + (size_t)4 * 1048576);  // 4 MiB offset; NN*96 floats

    k_zero <<<(NN + 255) / 256, 256, 0, stream>>>(cnt, cur);
    k_count<<<(NE + 255) / 256, 256, 0, stream>>>(ei + NE, cnt);
    k_scan <<<1, SCANT, 0, stream>>>(cnt, off);
    k_fill <<<(NE + 255) / 256, 256, 0, stream>>>(ei, off, cur, csr);
    k_gemm1<<<(NN * HH + 255) / 256, 256, 0, stream>>>(x, Wg, cnt, hp);
    k_mlp  <<<(NN + NPB - 1) / NPB, 128, 0, stream>>>(hp, cnt, off, csr, x, tmp,
                                                      bg, W1, b1, W2, b2, out);
}

// Round 4
// 473.316 us; speedup vs baseline: 3.2759x; 1.7639x over previous
//
#include <hip/hip_runtime.h>
#include <hip/hip_bf16.h>

#define NN 50000
#define NE 800000
#define NF 128
#define HH 96
#define TF 10
#define Z1DIM (HH + TF)   // 106
#define Z2DIM (HH + NF)   // 224

__device__ __forceinline__ float b2f(const __hip_bfloat16 v) { return __bfloat162float(v); }

// ---- kernel 1: zero cnt & cur ----
__global__ void k_zero(int* __restrict__ cnt, int* __restrict__ cur) {
    int i = blockIdx.x * 256 + threadIdx.x;
    if (i < NN) { cnt[i] = 0; cur[i] = 0; }
}

// ---- kernel 2: cnt[dst]++ over real edges ----
__global__ void k_count(const int* __restrict__ dst, int* __restrict__ cnt) {
    int e = blockIdx.x * 256 + threadIdx.x;
    if (e < NE) atomicAdd(&cnt[dst[e]], 1);
}

// ---- kernel 3: exclusive scan of cnt -> off (single block) ----
#define SCANT 1024
#define CHUNK ((NN + SCANT - 1) / SCANT)   // 49
__global__ __launch_bounds__(SCANT) void k_scan(const int* __restrict__ cnt,
                                                int* __restrict__ off) {
    __shared__ int partial[SCANT];
    const int t = threadIdx.x;
    const int lo = t * CHUNK;
    const int hi = min(lo + CHUNK, NN);
    int s = 0;
    for (int i = lo; i < hi; ++i) s += cnt[i];
    partial[t] = s;
    __syncthreads();
    for (int d = 1; d < SCANT; d <<= 1) {
        int v = (t >= d) ? partial[t - d] : 0;
        __syncthreads();
        partial[t] += v;
        __syncthreads();
    }
    int base = (t > 0) ? partial[t - 1] : 0;
    for (int i = lo; i < hi; ++i) { off[i] = base; base += cnt[i]; }
    if (t == SCANT - 1) off[NN] = base;
}

// ---- kernel 4: scatter edge src ids into CSR slots ----
__global__ void k_fill(const int* __restrict__ ei, const int* __restrict__ off,
                       int* __restrict__ cur, int* __restrict__ csr) {
    int e = blockIdx.x * 256 + threadIdx.x;
    if (e >= NE) return;
    int s = ei[e];
    int d = ei[NE + e];
    int slot = off[d] + atomicAdd(&cur[d], 1);
    csr[slot] = s;
}

// ---- kernel 5: hp = bf16( (x @ W_gcn) * rsqrt(deg[row]) ), W staged in LDS ----
#define GM 8
__global__ __launch_bounds__(192) void k_gemm1(const float* __restrict__ x,
                                               const float* __restrict__ W,
                                               const int* __restrict__ cnt,
                                               __hip_bfloat16* __restrict__ hp) {
    __shared__ float sW[NF * HH];  // 49152 B
    const int t = threadIdx.x;
    for (int m = t; m < NF * HH / 4; m += 192)
        ((float4*)sW)[m] = ((const float4*)W)[m];
    __syncthreads();
    const int j = t % HH;       // output column
    const int half = t / HH;    // 0/1 -> which 4-node subset
    const int i0 = blockIdx.x * GM + half * 4;
    const float* xr = x + (size_t)i0 * NF;
    float s0 = 0.f, s1 = 0.f, s2 = 0.f, s3 = 0.f;
#pragma unroll 8
    for (int k4 = 0; k4 < NF / 4; ++k4) {
        float4 a0 = ((const float4*)(xr))[k4];
        float4 a1 = ((const float4*)(xr + NF))[k4];
        float4 a2 = ((const float4*)(xr + 2 * NF))[k4];
        float4 a3 = ((const float4*)(xr + 3 * NF))[k4];
        int k = k4 * 4;
        float w0 = sW[(k + 0) * HH + j];
        float w1 = sW[(k + 1) * HH + j];
        float w2 = sW[(k + 2) * HH + j];
        float w3 = sW[(k + 3) * HH + j];
        s0 = fmaf(a0.x, w0, s0); s0 = fmaf(a0.y, w1, s0);
        s0 = fmaf(a0.z, w2, s0); s0 = fmaf(a0.w, w3, s0);
        s1 = fmaf(a1.x, w0, s1); s1 = fmaf(a1.y, w1, s1);
        s1 = fmaf(a1.z, w2, s1); s1 = fmaf(a1.w, w3, s1);
        s2 = fmaf(a2.x, w0, s2); s2 = fmaf(a2.y, w1, s2);
        s2 = fmaf(a2.z, w2, s2); s2 = fmaf(a2.w, w3, s2);
        s3 = fmaf(a3.x, w0, s3); s3 = fmaf(a3.y, w1, s3);
        s3 = fmaf(a3.z, w2, s3); s3 = fmaf(a3.w, w3, s3);
    }
    float r0 = rsqrtf((float)cnt[i0 + 0] + 1.f);
    float r1 = rsqrtf((float)cnt[i0 + 1] + 1.f);
    float r2 = rsqrtf((float)cnt[i0 + 2] + 1.f);
    float r3 = rsqrtf((float)cnt[i0 + 3] + 1.f);
    hp[(size_t)(i0 + 0) * HH + j] = __float2bfloat16(s0 * r0);
    hp[(size_t)(i0 + 1) * HH + j] = __float2bfloat16(s1 * r1);
    hp[(size_t)(i0 + 2) * HH + j] = __float2bfloat16(s2 * r2);
    hp[(size_t)(i0 + 3) * HH + j] = __float2bfloat16(s3 * r3);
}

// ---- kernel 6: gather-aggregate + GCN epilogue: agg = relu(dinv*sum + bg) ----
__global__ void k_agg(const __hip_bfloat16* __restrict__ hp,
                      const int* __restrict__ cnt, const int* __restrict__ off,
                      const int* __restrict__ csr, const float* __restrict__ bg,
                      float* __restrict__ agg) {
    int t = blockIdx.x * 256 + threadIdx.x;
    if (t >= NN * HH) return;
    int i = t / HH;
    int j = t - i * HH;
    float s = b2f(hp[t]);  // self-loop term
    int idx = off[i];
    const int c = cnt[i];
    const int end = idx + c;
    for (; idx + 3 < end; idx += 4) {
        int e0 = csr[idx], e1 = csr[idx + 1], e2 = csr[idx + 2], e3 = csr[idx + 3];
        float v0 = b2f(hp[(size_t)e0 * HH + j]);
        float v1 = b2f(hp[(size_t)e1 * HH + j]);
        float v2 = b2f(hp[(size_t)e2 * HH + j]);
        float v3 = b2f(hp[(size_t)e3 * HH + j]);
        s += (v0 + v1) + (v2 + v3);
    }
    for (; idx < end; ++idx) s += b2f(hp[(size_t)csr[idx] * HH + j]);
    float dinv = rsqrtf((float)c + 1.f);
    agg[t] = fmaxf(fmaf(dinv, s, bg[j]), 0.f);
}

// ---- kernel 7: MLP head. 512 thr = 4 groups x 128; each group GEMVs node PAIRS ----
#define MB 512
#define GPB 4
#define GN 8   // nodes per group
__global__ __launch_bounds__(MB) void k_mlp(
    const float* __restrict__ agg, const float* __restrict__ x,
    const float* __restrict__ tmp, const float* __restrict__ W1,
    const float* __restrict__ b1, const float* __restrict__ W2,
    const float* __restrict__ b2, float* __restrict__ out) {
    __shared__ float sW1[Z1DIM * HH];          // 40704 B
    __shared__ float sW2[Z2DIM];
    __shared__ float sb1[HH];
    __shared__ float sz[GPB][2][Z1DIM + 2];
    __shared__ float sa[GPB][2][HH];
    __shared__ float sred[GPB][2][2];
    const int t = threadIdx.x;
    for (int m = t; m < Z1DIM * HH / 4; m += MB)
        ((float4*)sW1)[m] = ((const float4*)W1)[m];
    if (t < Z2DIM) sW2[t] = W2[t];
    else if (t < Z2DIM + HH) sb1[t - Z2DIM] = b1[t - Z2DIM];
    __syncthreads();
    const float bias2 = b2[0];
    const int g = t >> 7, l = t & 127;
    const int gbase = (blockIdx.x * GPB + g) * GN;

    for (int p = 0; p < GN / 2; ++p) {
        const int i0 = gbase + 2 * p, i1 = i0 + 1;
        const bool v0 = i0 < NN, v1 = i1 < NN;
        if (l < HH) {
            sz[g][0][l] = v0 ? agg[(size_t)i0 * HH + l] : 0.f;
            sz[g][1][l] = v1 ? agg[(size_t)i1 * HH + l] : 0.f;
        } else if (l < Z1DIM) {
            sz[g][0][l] = v0 ? tmp[(size_t)i0 * TF + (l - HH)] : 0.f;
            sz[g][1][l] = v1 ? tmp[(size_t)i1 * TF + (l - HH)] : 0.f;
        }
        __syncthreads();
        if (l < HH) {
            float s0 = sb1[l], s1 = sb1[l];
#pragma unroll 2
            for (int k = 0; k < Z1DIM; ++k) {
                float w = sW1[k * HH + l];
                s0 = fmaf(sz[g][0][k], w, s0);
                s1 = fmaf(sz[g][1][k], w, s1);
            }
            sa[g][0][l] = fmaxf(s0, 0.f);
            sa[g][1][l] = fmaxf(s1, 0.f);
        }
        __syncthreads();
        float p0, p1;
        {
            float w = sW2[l];
            float z0 = (l < HH) ? sa[g][0][l] : (v0 ? x[(size_t)i0 * NF + (l - HH)] : 0.f);
            float z1 = (l < HH) ? sa[g][1][l] : (v1 ? x[(size_t)i1 * NF + (l - HH)] : 0.f);
            p0 = z0 * w; p1 = z1 * w;
            int k = l + 128;
            if (k < Z2DIM) {   // l < 96, source is x
                float w2 = sW2[k];
                float y0 = v0 ? x[(size_t)i0 * NF + (k - HH)] : 0.f;
                float y1 = v1 ? x[(size_t)i1 * NF + (k - HH)] : 0.f;
                p0 = fmaf(y0, w2, p0); p1 = fmaf(y1, w2, p1);
            }
        }
#pragma unroll
        for (int o = 32; o > 0; o >>= 1) {
            p0 += __shfl_down(p0, o, 64);
            p1 += __shfl_down(p1, o, 64);
        }
        if ((l & 63) == 0) { sred[g][0][l >> 6] = p0; sred[g][1][l >> 6] = p1; }
        __syncthreads();
        if (l == 0) {
            if (v0) out[i0] = fmaxf(sred[g][0][0] + sred[g][0][1] + bias2, 0.f);
            if (v1) out[i1] = fmaxf(sred[g][1][0] + sred[g][1][1] + bias2, 0.f);
        }
    }
}

extern "C" void kernel_launch(void* const* d_in, const int* in_sizes, int n_in,
                              void* d_out, int out_size, void* d_ws, size_t ws_size,
                              hipStream_t stream) {
    const float* x   = (const float*)d_in[0];
    const int*   ei  = (const int*)d_in[1];
    const float* tmp = (const float*)d_in[2];
    const float* Wg  = (const float*)d_in[3];
    const float* bg  = (const float*)d_in[4];
    const float* W1  = (const float*)d_in[5];
    const float* b1  = (const float*)d_in[6];
    const float* W2  = (const float*)d_in[7];
    const float* b2  = (const float*)d_in[8];
    float* out = (float*)d_out;

    int* cnt = (int*)d_ws;                 // [0,    65536)
    int* cur = cnt + 65536;                // [65536,131072)
    int* off = cur + 65536;                // NN+1
    int* csr = off + 65536;                // NE ints, ends < 4 MiB
    __hip_bfloat16* hp = (__hip_bfloat16*)((char*)d_ws + (size_t)4 * 1048576);  // NN*HH bf16 = 9.6 MB
    float* agg = (float*)((char*)d_ws + (size_t)4 * 1048576 + (size_t)2 * NN * HH); // NN*HH f32

    k_zero <<<(NN + 255) / 256, 256, 0, stream>>>(cnt, cur);
    k_count<<<(NE + 255) / 256, 256, 0, stream>>>(ei + NE, cnt);
    k_scan <<<1, SCANT, 0, stream>>>(cnt, off);
    k_fill <<<(NE + 255) / 256, 256, 0, stream>>>(ei, off, cur, csr);
    k_gemm1<<<NN / GM, 192, 0, stream>>>(x, Wg, cnt, hp);
    k_agg  <<<(NN * HH + 255) / 256, 256, 0, stream>>>(hp, cnt, off, csr, bg, agg);
    k_mlp  <<<(NN + GPB * GN - 1) / (GPB * GN), MB, 0, stream>>>(agg, x, tmp, W1, b1, W2, b2, out);
}

// Round 5
// 427.827 us; speedup vs baseline: 3.6242x; 1.1063x over previous
//
#include <hip/hip_runtime.h>
#include <hip/hip_bf16.h>

#define NN 50000
#define NPAD 50048           // 64-row padded for MFMA grid
#define NE 800000
#define NF 128
#define HH 96
#define TF 10
#define Z1DIM (HH + TF)   // 106
#define Z2DIM (HH + NF)   // 224

typedef __attribute__((ext_vector_type(8))) short short8;
typedef __attribute__((ext_vector_type(4))) float f32x4;

__device__ __forceinline__ float b2f(const __hip_bfloat16 v) { return __bfloat162float(v); }
__device__ __forceinline__ unsigned short f2bu(float f) {
    union { __hip_bfloat16 h; unsigned short u; } c;
    c.h = __float2bfloat16(f);
    return c.u;
}

// ---- kernel 1: zero cnt & cur ----
__global__ void k_zero(int* __restrict__ cnt, int* __restrict__ cur) {
    int i = blockIdx.x * 256 + threadIdx.x;
    if (i < NN) { cnt[i] = 0; cur[i] = 0; }
}

// ---- kernel 2: cnt[dst]++ over real edges ----
__global__ void k_count(const int* __restrict__ dst, int* __restrict__ cnt) {
    int e = blockIdx.x * 256 + threadIdx.x;
    if (e < NE) atomicAdd(&cnt[dst[e]], 1);
}

// ---- kernel 3: exclusive scan of cnt -> off; also dinv = rsqrt(cnt+1) ----
#define SCANT 1024
#define CHUNK ((NN + SCANT - 1) / SCANT)   // 49
__global__ __launch_bounds__(SCANT) void k_scan(const int* __restrict__ cnt,
                                                int* __restrict__ off,
                                                float* __restrict__ dinv) {
    __shared__ int partial[SCANT];
    const int t = threadIdx.x;
    const int lo = t * CHUNK;
    const int hi = min(lo + CHUNK, NN);
    int s = 0;
    for (int i = lo; i < hi; ++i) s += cnt[i];
    partial[t] = s;
    __syncthreads();
    for (int d = 1; d < SCANT; d <<= 1) {
        int v = (t >= d) ? partial[t - d] : 0;
        __syncthreads();
        partial[t] += v;
        __syncthreads();
    }
    int base = (t > 0) ? partial[t - 1] : 0;
    for (int i = lo; i < hi; ++i) {
        off[i] = base; base += cnt[i];
        dinv[i] = rsqrtf((float)cnt[i] + 1.0f);
    }
    if (t == SCANT - 1) off[NN] = base;
}

// ---- kernel 4: scatter edge src ids into CSR slots ----
__global__ void k_fill(const int* __restrict__ ei, const int* __restrict__ off,
                       int* __restrict__ cur, int* __restrict__ csr) {
    int e = blockIdx.x * 256 + threadIdx.x;
    if (e >= NE) return;
    int s = ei[e];
    int d = ei[NE + e];
    int slot = off[d] + atomicAdd(&cur[d], 1);
    csr[slot] = s;
}

// ---- kernel 5: prep — xb = bf16(x) padded, Wt = bf16(W_gcn)^T [n][k] ----
#define XBLK (NPAD * NF / 4 / 256)     // 6256
#define WBLK (NF * HH / 4 / 256)       // 12
__global__ void k_prep(const float* __restrict__ x, const float* __restrict__ W,
                       unsigned short* __restrict__ xb, unsigned short* __restrict__ Wt) {
    int b = blockIdx.x;
    if (b < XBLK) {
        int idx4 = (b * 256 + threadIdx.x) * 4;
        int row = idx4 >> 7;
        ushort4 v;
        if (row < NN) {
            float4 f = *(const float4*)(x + idx4);
            v.x = f2bu(f.x); v.y = f2bu(f.y); v.z = f2bu(f.z); v.w = f2bu(f.w);
        } else {
            v.x = v.y = v.z = v.w = 0;
        }
        *(ushort4*)(xb + idx4) = v;
    } else {
        int e = ((b - XBLK) * 256 + threadIdx.x) * 4;
        int n = e >> 7, k = e & 127;
        ushort4 v;
        v.x = f2bu(W[(k + 0) * HH + n]);
        v.y = f2bu(W[(k + 1) * HH + n]);
        v.z = f2bu(W[(k + 2) * HH + n]);
        v.w = f2bu(W[(k + 3) * HH + n]);
        *(ushort4*)(Wt + e) = v;
    }
}

// ---- kernel 6: MFMA GEMM. hp = bf16( (x @ W_gcn) * dinv[row] ) ----
// wave tile: 16 rows x 96 cols; 6 N-tiles x 4 K-steps of 16x16x32 bf16.
// A[m=lane&15][k=quad*8+j], B[n=lane&15][k=quad*8+j], D: col=lane&15,row=quad*4+reg
__global__ __launch_bounds__(256) void k_gemm(const unsigned short* __restrict__ xb,
                                              const unsigned short* __restrict__ Wt,
                                              const float* __restrict__ dinv,
                                              unsigned short* __restrict__ hp) {
    const int wave = threadIdx.x >> 6;
    const int lane = threadIdx.x & 63;
    const int quad = lane >> 4;
    const int l16 = lane & 15;
    const int Mbase = blockIdx.x * 64 + wave * 16;

    const unsigned short* arow = xb + (size_t)(Mbase + l16) * NF + quad * 8;
    const unsigned short* brow = Wt + (size_t)l16 * NF + quad * 8;

    f32x4 acc[6] = {};
#pragma unroll
    for (int ks = 0; ks < 4; ++ks) {
        short8 a = *(const short8*)(arow + ks * 32);
#pragma unroll
        for (int nt = 0; nt < 6; ++nt) {
            short8 bfrag = *(const short8*)(brow + (size_t)nt * 16 * NF + ks * 32);
            acc[nt] = __builtin_amdgcn_mfma_f32_16x16x32_bf16(a, bfrag, acc[nt], 0, 0, 0);
        }
    }
    const int r0 = Mbase + quad * 4;
    float dv0 = dinv[r0 + 0], dv1 = dinv[r0 + 1], dv2 = dinv[r0 + 2], dv3 = dinv[r0 + 3];
#pragma unroll
    for (int nt = 0; nt < 6; ++nt) {
        int n = nt * 16 + l16;
        if (r0 + 0 < NN) hp[(size_t)(r0 + 0) * HH + n] = f2bu(acc[nt][0] * dv0);
        if (r0 + 1 < NN) hp[(size_t)(r0 + 1) * HH + n] = f2bu(acc[nt][1] * dv1);
        if (r0 + 2 < NN) hp[(size_t)(r0 + 2) * HH + n] = f2bu(acc[nt][2] * dv2);
        if (r0 + 3 < NN) hp[(size_t)(r0 + 3) * HH + n] = f2bu(acc[nt][3] * dv3);
    }
}

// ---- kernel 7: gather-aggregate + GCN epilogue: agg = relu(dinv*sum + bg) ----
__global__ void k_agg(const __hip_bfloat16* __restrict__ hp,
                      const int* __restrict__ cnt, const int* __restrict__ off,
                      const int* __restrict__ csr, const float* __restrict__ dinv,
                      const float* __restrict__ bg, float* __restrict__ agg) {
    int t = blockIdx.x * 256 + threadIdx.x;
    if (t >= NN * HH) return;
    int i = t / HH;
    int j = t - i * HH;
    float s = b2f(hp[t]);  // self-loop term
    int idx = off[i];
    const int c = cnt[i];
    const int end = idx + c;
    for (; idx + 3 < end; idx += 4) {
        int e0 = csr[idx], e1 = csr[idx + 1], e2 = csr[idx + 2], e3 = csr[idx + 3];
        float v0 = b2f(hp[(size_t)e0 * HH + j]);
        float v1 = b2f(hp[(size_t)e1 * HH + j]);
        float v2 = b2f(hp[(size_t)e2 * HH + j]);
        float v3 = b2f(hp[(size_t)e3 * HH + j]);
        s += (v0 + v1) + (v2 + v3);
    }
    for (; idx < end; ++idx) s += b2f(hp[(size_t)csr[idx] * HH + j]);
    agg[t] = fmaxf(fmaf(dinv[i], s, bg[j]), 0.f);
}

// ---- kernel 8: MLP head. 512 thr = 4 groups x 128; each group GEMVs node PAIRS ----
#define MB 512
#define GPB 4
#define GN 8   // nodes per group
__global__ __launch_bounds__(MB) void k_mlp(
    const float* __restrict__ agg, const float* __restrict__ x,
    const float* __restrict__ tmp, const float* __restrict__ W1,
    const float* __restrict__ b1, const float* __restrict__ W2,
    const float* __restrict__ b2, float* __restrict__ out) {
    __shared__ float sW1[Z1DIM * HH];          // 40704 B
    __shared__ float sW2[Z2DIM];
    __shared__ float sb1[HH];
    __shared__ float sz[GPB][2][Z1DIM + 2];
    __shared__ float sa[GPB][2][HH];
    __shared__ float sred[GPB][2][2];
    const int t = threadIdx.x;
    for (int m = t; m < Z1DIM * HH / 4; m += MB)
        ((float4*)sW1)[m] = ((const float4*)W1)[m];
    if (t < Z2DIM) sW2[t] = W2[t];
    else if (t < Z2DIM + HH) sb1[t - Z2DIM] = b1[t - Z2DIM];
    __syncthreads();
    const float bias2 = b2[0];
    const int g = t >> 7, l = t & 127;
    const int gbase = (blockIdx.x * GPB + g) * GN;

    for (int p = 0; p < GN / 2; ++p) {
        const int i0 = gbase + 2 * p, i1 = i0 + 1;
        const bool v0 = i0 < NN, v1 = i1 < NN;
        if (l < HH) {
            sz[g][0][l] = v0 ? agg[(size_t)i0 * HH + l] : 0.f;
            sz[g][1][l] = v1 ? agg[(size_t)i1 * HH + l] : 0.f;
        } else if (l < Z1DIM) {
            sz[g][0][l] = v0 ? tmp[(size_t)i0 * TF + (l - HH)] : 0.f;
            sz[g][1][l] = v1 ? tmp[(size_t)i1 * TF + (l - HH)] : 0.f;
        }
        __syncthreads();
        if (l < HH) {
            float s0 = sb1[l], s1 = sb1[l];
#pragma unroll 2
            for (int k = 0; k < Z1DIM; ++k) {
                float w = sW1[k * HH + l];
                s0 = fmaf(sz[g][0][k], w, s0);
                s1 = fmaf(sz[g][1][k], w, s1);
            }
            sa[g][0][l] = fmaxf(s0, 0.f);
            sa[g][1][l] = fmaxf(s1, 0.f);
        }
        __syncthreads();
        float p0, p1;
        {
            float w = sW2[l];
            float z0 = (l < HH) ? sa[g][0][l] : (v0 ? x[(size_t)i0 * NF + (l - HH)] : 0.f);
            float z1 = (l < HH) ? sa[g][1][l] : (v1 ? x[(size_t)i1 * NF + (l - HH)] : 0.f);
            p0 = z0 * w; p1 = z1 * w;
            int k = l + 128;
            if (k < Z2DIM) {   // l < 96, source is x
                float w2 = sW2[k];
                float y0 = v0 ? x[(size_t)i0 * NF + (k - HH)] : 0.f;
                float y1 = v1 ? x[(size_t)i1 * NF + (k - HH)] : 0.f;
                p0 = fmaf(y0, w2, p0); p1 = fmaf(y1, w2, p1);
            }
        }
#pragma unroll
        for (int o = 32; o > 0; o >>= 1) {
            p0 += __shfl_down(p0, o, 64);
            p1 += __shfl_down(p1, o, 64);
        }
        if ((l & 63) == 0) { sred[g][0][l >> 6] = p0; sred[g][1][l >> 6] = p1; }
        __syncthreads();
        if (l == 0) {
            if (v0) out[i0] = fmaxf(sred[g][0][0] + sred[g][0][1] + bias2, 0.f);
            if (v1) out[i1] = fmaxf(sred[g][1][0] + sred[g][1][1] + bias2, 0.f);
        }
    }
}

extern "C" void kernel_launch(void* const* d_in, const int* in_sizes, int n_in,
                              void* d_out, int out_size, void* d_ws, size_t ws_size,
                              hipStream_t stream) {
    const float* x   = (const float*)d_in[0];
    const int*   ei  = (const int*)d_in[1];
    const float* tmp = (const float*)d_in[2];
    const float* Wg  = (const float*)d_in[3];
    const float* bg  = (const float*)d_in[4];
    const float* W1  = (const float*)d_in[5];
    const float* b1  = (const float*)d_in[6];
    const float* W2  = (const float*)d_in[7];
    const float* b2  = (const float*)d_in[8];
    float* out = (float*)d_out;

    char* base = (char*)d_ws;
    int* cnt = (int*)base;                 // 65536 ints
    int* cur = cnt + 65536;
    int* off = cur + 65536;
    int* csr = off + 65536;                // NE ints; ends < 4 MiB
    float* dinv = (float*)(base + ((size_t)4 << 20));            // 65536 floats
    unsigned short* xb = (unsigned short*)(base + ((size_t)4 << 20) + 262144);  // NPAD*NF bf16 = 12.8 MB
    unsigned short* Wt = xb + (size_t)NPAD * NF;                 // NF*HH bf16
    unsigned short* hp = Wt + NF * HH;                           // NN*HH bf16 = 9.6 MB
    float* agg = (float*)(hp + (size_t)NN * HH);                 // NN*HH f32 = 19.2 MB

    k_zero <<<(NN + 255) / 256, 256, 0, stream>>>(cnt, cur);
    k_count<<<(NE + 255) / 256, 256, 0, stream>>>(ei + NE, cnt);
    k_scan <<<1, SCANT, 0, stream>>>(cnt, off, dinv);
    k_fill <<<(NE + 255) / 256, 256, 0, stream>>>(ei, off, cur, csr);
    k_prep <<<XBLK + WBLK, 256, 0, stream>>>(x, Wg, xb, Wt);
    k_gemm <<<NPAD / 64, 256, 0, stream>>>(xb, Wt, dinv, hp);
    k_agg  <<<(NN * HH + 255) / 256, 256, 0, stream>>>((const __hip_bfloat16*)hp, cnt, off, csr, dinv, bg, agg);
    k_mlp  <<<(NN + GPB * GN - 1) / (GPB * GN), MB, 0, stream>>>(agg, x, tmp, W1, b1, W2, b2, out);
}

// Round 6
// 339.512 us; speedup vs baseline: 4.5670x; 1.2601x over previous
//
#include <hip/hip_runtime.h>
#include <hip/hip_bf16.h>

#define NN 50000
#define NPAD 50048           // 64-row padded for MFMA grid
#define NE 800000
#define NF 128
#define HH 96
#define TF 10
#define Z1DIM (HH + TF)   // 106
#define Z2DIM (HH + NF)   // 224
#define NB ((NN + 255) / 256)   // 196 scan blocks

typedef __attribute__((ext_vector_type(8))) short short8;
typedef __attribute__((ext_vector_type(4))) float f32x4;

__device__ __forceinline__ float b2f(const __hip_bfloat16 v) { return __bfloat162float(v); }
__device__ __forceinline__ unsigned short f2bu(float f) {
    union { __hip_bfloat16 h; unsigned short u; } c;
    c.h = __float2bfloat16(f);
    return c.u;
}

// ---- kernel 1: zero cnt & cur ----
__global__ void k_zero(int* __restrict__ cnt, int* __restrict__ cur) {
    int i = blockIdx.x * 256 + threadIdx.x;
    if (i < NN) { cnt[i] = 0; cur[i] = 0; }
}

// ---- kernel 2: cnt[dst]++ over real edges ----
__global__ void k_count(const int* __restrict__ dst, int* __restrict__ cnt) {
    int e = blockIdx.x * 256 + threadIdx.x;
    if (e < NE) atomicAdd(&cnt[dst[e]], 1);
}

// ---- kernel 3a: per-block sums of cnt ----
__global__ __launch_bounds__(256) void k_bsum(const int* __restrict__ cnt,
                                              int* __restrict__ bsum) {
    int i = blockIdx.x * 256 + threadIdx.x;
    int v = (i < NN) ? cnt[i] : 0;
#pragma unroll
    for (int o = 32; o > 0; o >>= 1) v += __shfl_down(v, o, 64);
    __shared__ int wsum[4];
    if ((threadIdx.x & 63) == 0) wsum[threadIdx.x >> 6] = v;
    __syncthreads();
    if (threadIdx.x == 0)
        bsum[blockIdx.x] = wsum[0] + wsum[1] + wsum[2] + wsum[3];
}

// ---- kernel 3b: exclusive scan of the NB block sums (single tiny block) ----
__global__ __launch_bounds__(256) void k_bscan(const int* __restrict__ bsum,
                                               int* __restrict__ bbase) {
    __shared__ int p[256];
    const int t = threadIdx.x;
    int v = (t < NB) ? bsum[t] : 0;
    p[t] = v;
    __syncthreads();
#pragma unroll
    for (int d = 1; d < 256; d <<= 1) {
        int u = (t >= d) ? p[t - d] : 0;
        __syncthreads();
        p[t] += u;
        __syncthreads();
    }
    if (t <= NB) bbase[t] = (t == 0) ? 0 : p[t - 1];
}

// ---- kernel 3c: intra-block scan + base -> off; also dinv ----
__global__ __launch_bounds__(256) void k_off(const int* __restrict__ cnt,
                                             const int* __restrict__ bbase,
                                             int* __restrict__ off,
                                             float* __restrict__ dinv) {
    __shared__ int p[256];
    const int t = threadIdx.x;
    const int i = blockIdx.x * 256 + t;
    int v = (i < NN) ? cnt[i] : 0;
    p[t] = v;
    __syncthreads();
#pragma unroll
    for (int d = 1; d < 256; d <<= 1) {
        int u = (t >= d) ? p[t - d] : 0;
        __syncthreads();
        p[t] += u;
        __syncthreads();
    }
    if (i < NN) {
        off[i] = bbase[blockIdx.x] + p[t] - v;   // exclusive
        dinv[i] = rsqrtf((float)v + 1.0f);
    }
    if (i == NN) off[NN] = bbase[NB];
    if (blockIdx.x == NB - 1 && t == 255) off[NN] = bbase[NB];
}

// ---- kernel 4: scatter edge src ids into CSR slots ----
__global__ void k_fill(const int* __restrict__ ei, const int* __restrict__ off,
                       int* __restrict__ cur, int* __restrict__ csr) {
    int e = blockIdx.x * 256 + threadIdx.x;
    if (e >= NE) return;
    int s = ei[e];
    int d = ei[NE + e];
    int slot = off[d] + atomicAdd(&cur[d], 1);
    csr[slot] = s;
}

// ---- kernel 5: prep — xb = bf16(x) padded, Wt = bf16(W_gcn)^T [n][k] ----
#define XBLK (NPAD * NF / 4 / 256)     // 6256
#define WBLK (NF * HH / 4 / 256)       // 12
__global__ void k_prep(const float* __restrict__ x, const float* __restrict__ W,
                       unsigned short* __restrict__ xb, unsigned short* __restrict__ Wt) {
    int b = blockIdx.x;
    if (b < XBLK) {
        int idx4 = (b * 256 + threadIdx.x) * 4;
        int row = idx4 >> 7;
        ushort4 v;
        if (row < NN) {
            float4 f = *(const float4*)(x + idx4);
            v.x = f2bu(f.x); v.y = f2bu(f.y); v.z = f2bu(f.z); v.w = f2bu(f.w);
        } else {
            v.x = v.y = v.z = v.w = 0;
        }
        *(ushort4*)(xb + idx4) = v;
    } else {
        int e = ((b - XBLK) * 256 + threadIdx.x) * 4;
        int n = e >> 7, k = e & 127;
        ushort4 v;
        v.x = f2bu(W[(k + 0) * HH + n]);
        v.y = f2bu(W[(k + 1) * HH + n]);
        v.z = f2bu(W[(k + 2) * HH + n]);
        v.w = f2bu(W[(k + 3) * HH + n]);
        *(ushort4*)(Wt + e) = v;
    }
}

// ---- kernel 6: MFMA GEMM. hp = bf16( (x @ W_gcn) * dinv[row] ) ----
__global__ __launch_bounds__(256) void k_gemm(const unsigned short* __restrict__ xb,
                                              const unsigned short* __restrict__ Wt,
                                              const float* __restrict__ dinv,
                                              unsigned short* __restrict__ hp) {
    const int wave = threadIdx.x >> 6;
    const int lane = threadIdx.x & 63;
    const int quad = lane >> 4;
    const int l16 = lane & 15;
    const int Mbase = blockIdx.x * 64 + wave * 16;

    const unsigned short* arow = xb + (size_t)(Mbase + l16) * NF + quad * 8;
    const unsigned short* brow = Wt + (size_t)l16 * NF + quad * 8;

    f32x4 acc[6] = {};
#pragma unroll
    for (int ks = 0; ks < 4; ++ks) {
        short8 a = *(const short8*)(arow + ks * 32);
#pragma unroll
        for (int nt = 0; nt < 6; ++nt) {
            short8 bfrag = *(const short8*)(brow + (size_t)nt * 16 * NF + ks * 32);
            acc[nt] = __builtin_amdgcn_mfma_f32_16x16x32_bf16(a, bfrag, acc[nt], 0, 0, 0);
        }
    }
    const int r0 = Mbase + quad * 4;
    float dv0 = dinv[r0 + 0], dv1 = dinv[r0 + 1], dv2 = dinv[r0 + 2], dv3 = dinv[r0 + 3];
#pragma unroll
    for (int nt = 0; nt < 6; ++nt) {
        int n = nt * 16 + l16;
        if (r0 + 0 < NN) hp[(size_t)(r0 + 0) * HH + n] = f2bu(acc[nt][0] * dv0);
        if (r0 + 1 < NN) hp[(size_t)(r0 + 1) * HH + n] = f2bu(acc[nt][1] * dv1);
        if (r0 + 2 < NN) hp[(size_t)(r0 + 2) * HH + n] = f2bu(acc[nt][2] * dv2);
        if (r0 + 3 < NN) hp[(size_t)(r0 + 3) * HH + n] = f2bu(acc[nt][3] * dv3);
    }
}

// ---- kernel 7: gather-aggregate + GCN epilogue: agg = relu(dinv*sum + bg) ----
__global__ void k_agg(const __hip_bfloat16* __restrict__ hp,
                      const int* __restrict__ cnt, const int* __restrict__ off,
                      const int* __restrict__ csr, const float* __restrict__ dinv,
                      const float* __restrict__ bg, float* __restrict__ agg) {
    int t = blockIdx.x * 256 + threadIdx.x;
    if (t >= NN * HH) return;
    int i = t / HH;
    int j = t - i * HH;
    float s = b2f(hp[t]);  // self-loop term
    int idx = off[i];
    const int c = cnt[i];
    const int end = idx + c;
    for (; idx + 3 < end; idx += 4) {
        int e0 = csr[idx], e1 = csr[idx + 1], e2 = csr[idx + 2], e3 = csr[idx + 3];
        float v0 = b2f(hp[(size_t)e0 * HH + j]);
        float v1 = b2f(hp[(size_t)e1 * HH + j]);
        float v2 = b2f(hp[(size_t)e2 * HH + j]);
        float v3 = b2f(hp[(size_t)e3 * HH + j]);
        s += (v0 + v1) + (v2 + v3);
    }
    for (; idx < end; ++idx) s += b2f(hp[(size_t)csr[idx] * HH + j]);
    agg[t] = fmaxf(fmaf(dinv[i], s, bg[j]), 0.f);
}

// ---- kernel 8: MLP head. 512 thr = 4 groups x 128; each group GEMVs node PAIRS ----
#define MB 512
#define GPB 4
#define GN 8   // nodes per group
__global__ __launch_bounds__(MB) void k_mlp(
    const float* __restrict__ agg, const float* __restrict__ x,
    const float* __restrict__ tmp, const float* __restrict__ W1,
    const float* __restrict__ b1, const float* __restrict__ W2,
    const float* __restrict__ b2, float* __restrict__ out) {
    __shared__ float sW1[Z1DIM * HH];          // 40704 B
    __shared__ float sW2[Z2DIM];
    __shared__ float sb1[HH];
    __shared__ float sz[GPB][2][Z1DIM + 2];
    __shared__ float sa[GPB][2][HH];
    __shared__ float sred[GPB][2][2];
    const int t = threadIdx.x;
    for (int m = t; m < Z1DIM * HH / 4; m += MB)
        ((float4*)sW1)[m] = ((const float4*)W1)[m];
    if (t < Z2DIM) sW2[t] = W2[t];
    else if (t < Z2DIM + HH) sb1[t - Z2DIM] = b1[t - Z2DIM];
    __syncthreads();
    const float bias2 = b2[0];
    const int g = t >> 7, l = t & 127;
    const int gbase = (blockIdx.x * GPB + g) * GN;

    for (int p = 0; p < GN / 2; ++p) {
        const int i0 = gbase + 2 * p, i1 = i0 + 1;
        const bool v0 = i0 < NN, v1 = i1 < NN;
        if (l < HH) {
            sz[g][0][l] = v0 ? agg[(size_t)i0 * HH + l] : 0.f;
            sz[g][1][l] = v1 ? agg[(size_t)i1 * HH + l] : 0.f;
        } else if (l < Z1DIM) {
            sz[g][0][l] = v0 ? tmp[(size_t)i0 * TF + (l - HH)] : 0.f;
            sz[g][1][l] = v1 ? tmp[(size_t)i1 * TF + (l - HH)] : 0.f;
        }
        __syncthreads();
        if (l < HH) {
            float s0 = sb1[l], s1 = sb1[l];
#pragma unroll 2
            for (int k = 0; k < Z1DIM; ++k) {
                float w = sW1[k * HH + l];
                s0 = fmaf(sz[g][0][k], w, s0);
                s1 = fmaf(sz[g][1][k], w, s1);
            }
            sa[g][0][l] = fmaxf(s0, 0.f);
            sa[g][1][l] = fmaxf(s1, 0.f);
        }
        __syncthreads();
        float p0, p1;
        {
            float w = sW2[l];
            float z0 = (l < HH) ? sa[g][0][l] : (v0 ? x[(size_t)i0 * NF + (l - HH)] : 0.f);
            float z1 = (l < HH) ? sa[g][1][l] : (v1 ? x[(size_t)i1 * NF + (l - HH)] : 0.f);
            p0 = z0 * w; p1 = z1 * w;
            int k = l + 128;
            if (k < Z2DIM) {
                float w2 = sW2[k];
                float y0 = v0 ? x[(size_t)i0 * NF + (k - HH)] : 0.f;
                float y1 = v1 ? x[(size_t)i1 * NF + (k - HH)] : 0.f;
                p0 = fmaf(y0, w2, p0); p1 = fmaf(y1, w2, p1);
            }
        }
#pragma unroll
        for (int o = 32; o > 0; o >>= 1) {
            p0 += __shfl_down(p0, o, 64);
            p1 += __shfl_down(p1, o, 64);
        }
        if ((l & 63) == 0) { sred[g][0][l >> 6] = p0; sred[g][1][l >> 6] = p1; }
        __syncthreads();
        if (l == 0) {
            if (v0) out[i0] = fmaxf(sred[g][0][0] + sred[g][0][1] + bias2, 0.f);
            if (v1) out[i1] = fmaxf(sred[g][1][0] + sred[g][1][1] + bias2, 0.f);
        }
    }
}

extern "C" void kernel_launch(void* const* d_in, const int* in_sizes, int n_in,
                              void* d_out, int out_size, void* d_ws, size_t ws_size,
                              hipStream_t stream) {
    const float* x   = (const float*)d_in[0];
    const int*   ei  = (const int*)d_in[1];
    const float* tmp = (const float*)d_in[2];
    const float* Wg  = (const float*)d_in[3];
    const float* bg  = (const float*)d_in[4];
    const float* W1  = (const float*)d_in[5];
    const float* b1  = (const float*)d_in[6];
    const float* W2  = (const float*)d_in[7];
    const float* b2  = (const float*)d_in[8];
    float* out = (float*)d_out;

    char* base = (char*)d_ws;
    int* cnt = (int*)base;                 // 65536 ints
    int* cur = cnt + 65536;
    int* off = cur + 65536;
    int* csr = off + 65536;                // NE ints
    int* bsum = csr + NE;                  // NB ints
    int* bbase = bsum + 256;               // NB+1 ints (all < 4 MiB)
    float* dinv = (float*)(base + ((size_t)4 << 20));            // 65536 floats
    unsigned short* xb = (unsigned short*)(base + ((size_t)4 << 20) + 262144);  // NPAD*NF bf16
    unsigned short* Wt = xb + (size_t)NPAD * NF;                 // NF*HH bf16
    unsigned short* hp = Wt + NF * HH;                           // NN*HH bf16
    float* agg = (float*)(hp + (size_t)NN * HH);                 // NN*HH f32

    k_zero <<<(NN + 255) / 256, 256, 0, stream>>>(cnt, cur);
    k_count<<<(NE + 255) / 256, 256, 0, stream>>>(ei + NE, cnt);
    k_bsum <<<NB, 256, 0, stream>>>(cnt, bsum);
    k_bscan<<<1, 256, 0, stream>>>(bsum, bbase);
    k_off  <<<NB, 256, 0, stream>>>(cnt, bbase, off, dinv);
    k_fill <<<(NE + 255) / 256, 256, 0, stream>>>(ei, off, cur, csr);
    k_prep <<<XBLK + WBLK, 256, 0, stream>>>(x, Wg, xb, Wt);
    k_gemm <<<NPAD / 64, 256, 0, stream>>>(xb, Wt, dinv, hp);
    k_agg  <<<(NN * HH + 255) / 256, 256, 0, stream>>>((const __hip_bfloat16*)hp, cnt, off, csr, dinv, bg, agg);
    k_mlp  <<<(NN + GPB * GN - 1) / (GPB * GN), MB, 0, stream>>>(agg, x, tmp, W1, b1, W2, b2, out);
}

// Round 7
// 279.645 us; speedup vs baseline: 5.5447x; 1.2141x over previous
//
#include <hip/hip_runtime.h>
#include <hip/hip_bf16.h>

#define NN 50000
#define NPAD 50048           // 64-row padded for MFMA grid
#define NE 800000
#define NF 128
#define HH 96
#define TF 10
#define Z1DIM (HH + TF)   // 106
#define Z2DIM (HH + NF)   // 224
#define ZK 128            // padded K for layer-1 MFMA
#define NB ((NN + 255) / 256)   // 196 scan blocks

typedef __attribute__((ext_vector_type(8))) short short8;
typedef __attribute__((ext_vector_type(4))) float f32x4;

__device__ __forceinline__ float b2f(const __hip_bfloat16 v) { return __bfloat162float(v); }
__device__ __forceinline__ unsigned short f2bu(float f) {
    union { __hip_bfloat16 h; unsigned short u; } c;
    c.h = __float2bfloat16(f);
    return c.u;
}

// ---- kernel 1: zero cnt & cur ----
__global__ void k_zero(int* __restrict__ cnt, int* __restrict__ cur) {
    int i = blockIdx.x * 256 + threadIdx.x;
    if (i < NN) { cnt[i] = 0; cur[i] = 0; }
}

// ---- kernel 2: cnt[dst]++ over real edges ----
__global__ void k_count(const int* __restrict__ dst, int* __restrict__ cnt) {
    int e = blockIdx.x * 256 + threadIdx.x;
    if (e < NE) atomicAdd(&cnt[dst[e]], 1);
}

// ---- kernel 3a: per-block sums of cnt ----
__global__ __launch_bounds__(256) void k_bsum(const int* __restrict__ cnt,
                                              int* __restrict__ bsum) {
    int i = blockIdx.x * 256 + threadIdx.x;
    int v = (i < NN) ? cnt[i] : 0;
#pragma unroll
    for (int o = 32; o > 0; o >>= 1) v += __shfl_down(v, o, 64);
    __shared__ int wsum[4];
    if ((threadIdx.x & 63) == 0) wsum[threadIdx.x >> 6] = v;
    __syncthreads();
    if (threadIdx.x == 0)
        bsum[blockIdx.x] = wsum[0] + wsum[1] + wsum[2] + wsum[3];
}

// ---- kernel 3b: exclusive scan of the NB block sums (single tiny block) ----
__global__ __launch_bounds__(256) void k_bscan(const int* __restrict__ bsum,
                                               int* __restrict__ bbase) {
    __shared__ int p[256];
    const int t = threadIdx.x;
    int v = (t < NB) ? bsum[t] : 0;
    p[t] = v;
    __syncthreads();
#pragma unroll
    for (int d = 1; d < 256; d <<= 1) {
        int u = (t >= d) ? p[t - d] : 0;
        __syncthreads();
        p[t] += u;
        __syncthreads();
    }
    if (t <= NB && t > 0) bbase[t] = p[t - 1];
    if (t == 0) bbase[0] = 0;
}

// ---- kernel 3c: intra-block scan + base -> off; also dinv ----
__global__ __launch_bounds__(256) void k_off(const int* __restrict__ cnt,
                                             const int* __restrict__ bbase,
                                             int* __restrict__ off,
                                             float* __restrict__ dinv) {
    __shared__ int p[256];
    const int t = threadIdx.x;
    const int i = blockIdx.x * 256 + t;
    int v = (i < NN) ? cnt[i] : 0;
    p[t] = v;
    __syncthreads();
#pragma unroll
    for (int d = 1; d < 256; d <<= 1) {
        int u = (t >= d) ? p[t - d] : 0;
        __syncthreads();
        p[t] += u;
        __syncthreads();
    }
    if (i < NN) {
        off[i] = bbase[blockIdx.x] + p[t] - v;   // exclusive
        dinv[i] = rsqrtf((float)v + 1.0f);
    }
    if (blockIdx.x == NB - 1 && t == 255) off[NN] = bbase[NB];
}

// ---- kernel 4: scatter edge src ids into CSR slots ----
__global__ void k_fill(const int* __restrict__ ei, const int* __restrict__ off,
                       int* __restrict__ cur, int* __restrict__ csr) {
    int e = blockIdx.x * 256 + threadIdx.x;
    if (e >= NE) return;
    int s = ei[e];
    int d = ei[NE + e];
    int slot = off[d] + atomicAdd(&cur[d], 1);
    csr[slot] = s;
}

// ---- kernel 5: prep — xb = bf16(x) padded; Wt = bf16(Wg)^T; Wt1 = bf16(W1)^T K-padded ----
#define XBLK (NPAD * NF / 4 / 256)     // 6256
#define WBLK (NF * HH / 4 / 256)       // 12
#define W1BLK (HH * ZK / 4 / 256)      // 12
__global__ void k_prep(const float* __restrict__ x, const float* __restrict__ W,
                       const float* __restrict__ W1,
                       unsigned short* __restrict__ xb, unsigned short* __restrict__ Wt,
                       unsigned short* __restrict__ Wt1) {
    int b = blockIdx.x;
    if (b < XBLK) {
        int idx4 = (b * 256 + threadIdx.x) * 4;
        int row = idx4 >> 7;
        ushort4 v;
        if (row < NN) {
            float4 f = *(const float4*)(x + idx4);
            v.x = f2bu(f.x); v.y = f2bu(f.y); v.z = f2bu(f.z); v.w = f2bu(f.w);
        } else {
            v.x = v.y = v.z = v.w = 0;
        }
        *(ushort4*)(xb + idx4) = v;
    } else if (b < XBLK + WBLK) {
        int e = ((b - XBLK) * 256 + threadIdx.x) * 4;
        int n = e >> 7, k = e & 127;
        ushort4 v;
        v.x = f2bu(W[(k + 0) * HH + n]);
        v.y = f2bu(W[(k + 1) * HH + n]);
        v.z = f2bu(W[(k + 2) * HH + n]);
        v.w = f2bu(W[(k + 3) * HH + n]);
        *(ushort4*)(Wt + e) = v;
    } else {
        int e = ((b - XBLK - WBLK) * 256 + threadIdx.x) * 4;
        int n = e >> 7, k = e & 127;     // n in [0,96), k in [0,128)
        ushort4 v;
        v.x = (k + 0 < Z1DIM) ? f2bu(W1[(k + 0) * HH + n]) : (unsigned short)0;
        v.y = (k + 1 < Z1DIM) ? f2bu(W1[(k + 1) * HH + n]) : (unsigned short)0;
        v.z = (k + 2 < Z1DIM) ? f2bu(W1[(k + 2) * HH + n]) : (unsigned short)0;
        v.w = (k + 3 < Z1DIM) ? f2bu(W1[(k + 3) * HH + n]) : (unsigned short)0;
        *(ushort4*)(Wt1 + e) = v;
    }
}

// ---- kernel 6: MFMA GEMM. hp = bf16( (x @ W_gcn) * dinv[row] ) ----
__global__ __launch_bounds__(256) void k_gemm(const unsigned short* __restrict__ xb,
                                              const unsigned short* __restrict__ Wt,
                                              const float* __restrict__ dinv,
                                              unsigned short* __restrict__ hp) {
    const int wave = threadIdx.x >> 6;
    const int lane = threadIdx.x & 63;
    const int quad = lane >> 4;
    const int l16 = lane & 15;
    const int Mbase = blockIdx.x * 64 + wave * 16;

    const unsigned short* arow = xb + (size_t)(Mbase + l16) * NF + quad * 8;
    const unsigned short* brow = Wt + (size_t)l16 * NF + quad * 8;

    f32x4 acc[6] = {};
#pragma unroll
    for (int ks = 0; ks < 4; ++ks) {
        short8 a = *(const short8*)(arow + ks * 32);
#pragma unroll
        for (int nt = 0; nt < 6; ++nt) {
            short8 bfrag = *(const short8*)(brow + (size_t)nt * 16 * NF + ks * 32);
            acc[nt] = __builtin_amdgcn_mfma_f32_16x16x32_bf16(a, bfrag, acc[nt], 0, 0, 0);
        }
    }
    const int r0 = Mbase + quad * 4;
    float dv0 = (r0 + 0 < NN) ? dinv[r0 + 0] : 0.f;
    float dv1 = (r0 + 1 < NN) ? dinv[r0 + 1] : 0.f;
    float dv2 = (r0 + 2 < NN) ? dinv[r0 + 2] : 0.f;
    float dv3 = (r0 + 3 < NN) ? dinv[r0 + 3] : 0.f;
#pragma unroll
    for (int nt = 0; nt < 6; ++nt) {
        int n = nt * 16 + l16;
        if (r0 + 0 < NN) hp[(size_t)(r0 + 0) * HH + n] = f2bu(acc[nt][0] * dv0);
        if (r0 + 1 < NN) hp[(size_t)(r0 + 1) * HH + n] = f2bu(acc[nt][1] * dv1);
        if (r0 + 2 < NN) hp[(size_t)(r0 + 2) * HH + n] = f2bu(acc[nt][2] * dv2);
        if (r0 + 3 < NN) hp[(size_t)(r0 + 3) * HH + n] = f2bu(acc[nt][3] * dv3);
    }
}

// ---- kernel 7: gather-aggregate -> zb[i][128] = [relu GCN | temporal | 0] bf16 ----
__global__ void k_agg(const __hip_bfloat16* __restrict__ hp,
                      const int* __restrict__ cnt, const int* __restrict__ off,
                      const int* __restrict__ csr, const float* __restrict__ dinv,
                      const float* __restrict__ bg, const float* __restrict__ tmp,
                      unsigned short* __restrict__ zb) {
    int t = blockIdx.x * 256 + threadIdx.x;
    if (t >= NPAD * ZK) return;
    int i = t >> 7;
    int j = t & 127;
    if (i >= NN) { zb[t] = 0; return; }
    if (j < HH) {
        float s = b2f(hp[(size_t)i * HH + j]);  // self-loop term
        int idx = off[i];
        const int c = cnt[i];
        const int end = idx + c;
        for (; idx + 3 < end; idx += 4) {
            int e0 = csr[idx], e1 = csr[idx + 1], e2 = csr[idx + 2], e3 = csr[idx + 3];
            float v0 = b2f(hp[(size_t)e0 * HH + j]);
            float v1 = b2f(hp[(size_t)e1 * HH + j]);
            float v2 = b2f(hp[(size_t)e2 * HH + j]);
            float v3 = b2f(hp[(size_t)e3 * HH + j]);
            s += (v0 + v1) + (v2 + v3);
        }
        for (; idx < end; ++idx) s += b2f(hp[(size_t)csr[idx] * HH + j]);
        zb[t] = f2bu(fmaxf(fmaf(dinv[i], s, bg[j]), 0.f));
    } else if (j < Z1DIM) {
        zb[t] = f2bu(tmp[(size_t)i * TF + (j - HH)]);
    } else {
        zb[t] = 0;
    }
}

// ---- kernel 8: MFMA layer-1 + fused layer-2 dot epilogue ----
// a1 = relu(zb @ W1 + b1)  [in C-fragments, never stored]
// out[r] = relu( sum_c a1[r][c]*W2[c] + sum_k x[r][k]*W2[96+k] + b2 )
__global__ __launch_bounds__(256) void k_mlp2(const unsigned short* __restrict__ zb,
                                              const unsigned short* __restrict__ Wt1,
                                              const float* __restrict__ b1,
                                              const float* __restrict__ W2,
                                              const float* __restrict__ b2,
                                              const float* __restrict__ x,
                                              float* __restrict__ out) {
    const int wave = threadIdx.x >> 6;
    const int lane = threadIdx.x & 63;
    const int quad = lane >> 4;
    const int l16 = lane & 15;
    const int Mbase = blockIdx.x * 64 + wave * 16;

    const unsigned short* arow = zb + (size_t)(Mbase + l16) * ZK + quad * 8;
    const unsigned short* brow = Wt1 + (size_t)l16 * ZK + quad * 8;

    f32x4 acc[6] = {};
#pragma unroll
    for (int ks = 0; ks < 4; ++ks) {
        short8 a = *(const short8*)(arow + ks * 32);
#pragma unroll
        for (int nt = 0; nt < 6; ++nt) {
            short8 bfrag = *(const short8*)(brow + (size_t)nt * 16 * ZK + ks * 32);
            acc[nt] = __builtin_amdgcn_mfma_f32_16x16x32_bf16(a, bfrag, acc[nt], 0, 0, 0);
        }
    }
    // per-lane constants for my 6 columns + my 8-elem x chunk
    float bb[6], wa[6];
#pragma unroll
    for (int nt = 0; nt < 6; ++nt) {
        int c = nt * 16 + l16;
        bb[nt] = b1[c];
        wa[nt] = W2[c];
    }
    float wx[8];
#pragma unroll
    for (int m = 0; m < 8; ++m) wx[m] = W2[HH + l16 * 8 + m];
    const float bias2 = b2[0];

#pragma unroll
    for (int reg = 0; reg < 4; ++reg) {
        const int r = Mbase + quad * 4 + reg;
        float p = 0.f;
#pragma unroll
        for (int nt = 0; nt < 6; ++nt)
            p = fmaf(fmaxf(acc[nt][reg] + bb[nt], 0.f), wa[nt], p);
        if (r < NN) {
            const float4 xa = *(const float4*)(x + (size_t)r * NF + l16 * 8);
            const float4 xc = *(const float4*)(x + (size_t)r * NF + l16 * 8 + 4);
            p = fmaf(xa.x, wx[0], p); p = fmaf(xa.y, wx[1], p);
            p = fmaf(xa.z, wx[2], p); p = fmaf(xa.w, wx[3], p);
            p = fmaf(xc.x, wx[4], p); p = fmaf(xc.y, wx[5], p);
            p = fmaf(xc.z, wx[6], p); p = fmaf(xc.w, wx[7], p);
        }
#pragma unroll
        for (int m = 1; m < 16; m <<= 1) p += __shfl_xor(p, m, 64);
        if (l16 == 0 && r < NN) out[r] = fmaxf(p + bias2, 0.f);
    }
}

extern "C" void kernel_launch(void* const* d_in, const int* in_sizes, int n_in,
                              void* d_out, int out_size, void* d_ws, size_t ws_size,
                              hipStream_t stream) {
    const float* x   = (const float*)d_in[0];
    const int*   ei  = (const int*)d_in[1];
    const float* tmp = (const float*)d_in[2];
    const float* Wg  = (const float*)d_in[3];
    const float* bg  = (const float*)d_in[4];
    const float* W1  = (const float*)d_in[5];
    const float* b1  = (const float*)d_in[6];
    const float* W2  = (const float*)d_in[7];
    const float* b2  = (const float*)d_in[8];
    float* out = (float*)d_out;

    char* base = (char*)d_ws;
    int* cnt = (int*)base;                 // 65536 ints
    int* cur = cnt + 65536;
    int* off = cur + 65536;
    int* csr = off + 65536;                // NE ints
    int* bsum = csr + NE;                  // NB ints
    int* bbase = bsum + 256;               // NB+1 ints (all < 4 MiB)
    float* dinv = (float*)(base + ((size_t)4 << 20));            // 65536 floats
    unsigned short* xb = (unsigned short*)(base + ((size_t)4 << 20) + 262144);  // NPAD*NF bf16
    unsigned short* Wt = xb + (size_t)NPAD * NF;                 // NF*HH bf16
    unsigned short* hp = Wt + NF * HH;                           // NN*HH bf16
    unsigned short* Wt1 = hp + (size_t)NN * HH;                  // HH*ZK bf16
    unsigned short* zb = Wt1 + HH * ZK;                          // NPAD*ZK bf16

    k_zero <<<(NN + 255) / 256, 256, 0, stream>>>(cnt, cur);
    k_count<<<(NE + 255) / 256, 256, 0, stream>>>(ei + NE, cnt);
    k_bsum <<<NB, 256, 0, stream>>>(cnt, bsum);
    k_bscan<<<1, 256, 0, stream>>>(bsum, bbase);
    k_off  <<<NB, 256, 0, stream>>>(cnt, bbase, off, dinv);
    k_fill <<<(NE + 255) / 256, 256, 0, stream>>>(ei, off, cur, csr);
    k_prep <<<XBLK + WBLK + W1BLK, 256, 0, stream>>>(x, Wg, W1, xb, Wt, Wt1);
    k_gemm <<<NPAD / 64, 256, 0, stream>>>(xb, Wt, dinv, hp);
    k_agg  <<<(NPAD * ZK + 255) / 256, 256, 0, stream>>>((const __hip_bfloat16*)hp, cnt, off, csr, dinv, bg, tmp, zb);
    k_mlp2 <<<NPAD / 64, 256, 0, stream>>>(zb, Wt1, b1, W2, b2, x, out);
}

// Round 8
// 262.322 us; speedup vs baseline: 5.9108x; 1.0660x over previous
//
#include <hip/hip_runtime.h>
#include <hip/hip_bf16.h>

#define NN 50000
#define NPAD 50048           // 64-row padded for MFMA grid
#define NE 800000
#define NF 128
#define HH 96
#define TF 10
#define Z1DIM (HH + TF)   // 106
#define Z2DIM (HH + NF)   // 224
#define ZK 128            // padded K for layer-1 MFMA
#define NB ((NN + 255) / 256)   // 196 scan blocks
#define NCH 4             // column chunks for the gather
#define CW 24             // chunk width (cols): NCH*CW == HH

typedef __attribute__((ext_vector_type(8))) short short8;
typedef __attribute__((ext_vector_type(4))) float f32x4;

__device__ __forceinline__ float b2f(const __hip_bfloat16 v) { return __bfloat162float(v); }
__device__ __forceinline__ float bu2f(unsigned short u) {
    union { unsigned int i; float f; } c;
    c.i = ((unsigned int)u) << 16;
    return c.f;
}
__device__ __forceinline__ unsigned short f2bu(float f) {
    union { __hip_bfloat16 h; unsigned short u; } c;
    c.h = __float2bfloat16(f);
    return c.u;
}

// ---- kernel 1: zero cnt & cur ----
__global__ void k_zero(int* __restrict__ cnt, int* __restrict__ cur) {
    int i = blockIdx.x * 256 + threadIdx.x;
    if (i < NN) { cnt[i] = 0; cur[i] = 0; }
}

// ---- kernel 2: cnt[dst]++ over real edges ----
__global__ void k_count(const int* __restrict__ dst, int* __restrict__ cnt) {
    int e = blockIdx.x * 256 + threadIdx.x;
    if (e < NE) atomicAdd(&cnt[dst[e]], 1);
}

// ---- kernel 3a: per-block sums of cnt ----
__global__ __launch_bounds__(256) void k_bsum(const int* __restrict__ cnt,
                                              int* __restrict__ bsum) {
    int i = blockIdx.x * 256 + threadIdx.x;
    int v = (i < NN) ? cnt[i] : 0;
#pragma unroll
    for (int o = 32; o > 0; o >>= 1) v += __shfl_down(v, o, 64);
    __shared__ int wsum[4];
    if ((threadIdx.x & 63) == 0) wsum[threadIdx.x >> 6] = v;
    __syncthreads();
    if (threadIdx.x == 0)
        bsum[blockIdx.x] = wsum[0] + wsum[1] + wsum[2] + wsum[3];
}

// ---- kernel 3b: exclusive scan of the NB block sums ----
__global__ __launch_bounds__(256) void k_bscan(const int* __restrict__ bsum,
                                               int* __restrict__ bbase) {
    __shared__ int p[256];
    const int t = threadIdx.x;
    int v = (t < NB) ? bsum[t] : 0;
    p[t] = v;
    __syncthreads();
#pragma unroll
    for (int d = 1; d < 256; d <<= 1) {
        int u = (t >= d) ? p[t - d] : 0;
        __syncthreads();
        p[t] += u;
        __syncthreads();
    }
    if (t <= NB && t > 0) bbase[t] = p[t - 1];
    if (t == 0) bbase[0] = 0;
}

// ---- kernel 3c: intra-block scan + base -> off; also dinv ----
__global__ __launch_bounds__(256) void k_off(const int* __restrict__ cnt,
                                             const int* __restrict__ bbase,
                                             int* __restrict__ off,
                                             float* __restrict__ dinv) {
    __shared__ int p[256];
    const int t = threadIdx.x;
    const int i = blockIdx.x * 256 + t;
    int v = (i < NN) ? cnt[i] : 0;
    p[t] = v;
    __syncthreads();
#pragma unroll
    for (int d = 1; d < 256; d <<= 1) {
        int u = (t >= d) ? p[t - d] : 0;
        __syncthreads();
        p[t] += u;
        __syncthreads();
    }
    if (i < NN) {
        off[i] = bbase[blockIdx.x] + p[t] - v;   // exclusive
        dinv[i] = rsqrtf((float)v + 1.0f);
    }
    if (blockIdx.x == NB - 1 && t == 255) off[NN] = bbase[NB];
}

// ---- kernel 4: scatter edge src ids into CSR slots ----
__global__ void k_fill(const int* __restrict__ ei, const int* __restrict__ off,
                       int* __restrict__ cur, int* __restrict__ csr) {
    int e = blockIdx.x * 256 + threadIdx.x;
    if (e >= NE) return;
    int s = ei[e];
    int d = ei[NE + e];
    int slot = off[d] + atomicAdd(&cur[d], 1);
    csr[slot] = s;
}

// ---- kernel 5: prep — xb = bf16(x) padded; Wt = bf16(Wg)^T; Wt1 = bf16(W1)^T K-padded ----
#define XBLK (NPAD * NF / 4 / 256)     // 6256
#define WBLK (NF * HH / 4 / 256)       // 12
#define W1BLK (HH * ZK / 4 / 256)      // 12
__global__ void k_prep(const float* __restrict__ x, const float* __restrict__ W,
                       const float* __restrict__ W1,
                       unsigned short* __restrict__ xb, unsigned short* __restrict__ Wt,
                       unsigned short* __restrict__ Wt1) {
    int b = blockIdx.x;
    if (b < XBLK) {
        int idx4 = (b * 256 + threadIdx.x) * 4;
        int row = idx4 >> 7;
        ushort4 v;
        if (row < NN) {
            float4 f = *(const float4*)(x + idx4);
            v.x = f2bu(f.x); v.y = f2bu(f.y); v.z = f2bu(f.z); v.w = f2bu(f.w);
        } else {
            v.x = v.y = v.z = v.w = 0;
        }
        *(ushort4*)(xb + idx4) = v;
    } else if (b < XBLK + WBLK) {
        int e = ((b - XBLK) * 256 + threadIdx.x) * 4;
        int n = e >> 7, k = e & 127;
        ushort4 v;
        v.x = f2bu(W[(k + 0) * HH + n]);
        v.y = f2bu(W[(k + 1) * HH + n]);
        v.z = f2bu(W[(k + 2) * HH + n]);
        v.w = f2bu(W[(k + 3) * HH + n]);
        *(ushort4*)(Wt + e) = v;
    } else {
        int e = ((b - XBLK - WBLK) * 256 + threadIdx.x) * 4;
        int n = e >> 7, k = e & 127;     // n in [0,96), k in [0,128)
        ushort4 v;
        v.x = (k + 0 < Z1DIM) ? f2bu(W1[(k + 0) * HH + n]) : (unsigned short)0;
        v.y = (k + 1 < Z1DIM) ? f2bu(W1[(k + 1) * HH + n]) : (unsigned short)0;
        v.z = (k + 2 < Z1DIM) ? f2bu(W1[(k + 2) * HH + n]) : (unsigned short)0;
        v.w = (k + 3 < Z1DIM) ? f2bu(W1[(k + 3) * HH + n]) : (unsigned short)0;
        *(ushort4*)(Wt1 + e) = v;
    }
}

// ---- kernel 6: MFMA GEMM. hp_c[chunk][row][24] = bf16( (x @ Wg) * dinv[row] ) ----
__global__ __launch_bounds__(256) void k_gemm(const unsigned short* __restrict__ xb,
                                              const unsigned short* __restrict__ Wt,
                                              const float* __restrict__ dinv,
                                              unsigned short* __restrict__ hp_c) {
    const int wave = threadIdx.x >> 6;
    const int lane = threadIdx.x & 63;
    const int quad = lane >> 4;
    const int l16 = lane & 15;
    const int Mbase = blockIdx.x * 64 + wave * 16;

    const unsigned short* arow = xb + (size_t)(Mbase + l16) * NF + quad * 8;
    const unsigned short* brow = Wt + (size_t)l16 * NF + quad * 8;

    f32x4 acc[6] = {};
#pragma unroll
    for (int ks = 0; ks < 4; ++ks) {
        short8 a = *(const short8*)(arow + ks * 32);
#pragma unroll
        for (int nt = 0; nt < 6; ++nt) {
            short8 bfrag = *(const short8*)(brow + (size_t)nt * 16 * NF + ks * 32);
            acc[nt] = __builtin_amdgcn_mfma_f32_16x16x32_bf16(a, bfrag, acc[nt], 0, 0, 0);
        }
    }
    const int r0 = Mbase + quad * 4;
    float dv0 = (r0 + 0 < NN) ? dinv[r0 + 0] : 0.f;
    float dv1 = (r0 + 1 < NN) ? dinv[r0 + 1] : 0.f;
    float dv2 = (r0 + 2 < NN) ? dinv[r0 + 2] : 0.f;
    float dv3 = (r0 + 3 < NN) ? dinv[r0 + 3] : 0.f;
#pragma unroll
    for (int nt = 0; nt < 6; ++nt) {
        int n = nt * 16 + l16;
        int c = n / CW, jj = n - c * CW;
        unsigned short* dst = hp_c + (size_t)c * NN * CW + jj;
        if (r0 + 0 < NN) dst[(size_t)(r0 + 0) * CW] = f2bu(acc[nt][0] * dv0);
        if (r0 + 1 < NN) dst[(size_t)(r0 + 1) * CW] = f2bu(acc[nt][1] * dv1);
        if (r0 + 2 < NN) dst[(size_t)(r0 + 2) * CW] = f2bu(acc[nt][2] * dv2);
        if (r0 + 3 < NN) dst[(size_t)(r0 + 3) * CW] = f2bu(acc[nt][3] * dv3);
    }
}

// ---- kernel 7: chunked gather-aggregate -> zb[i][0..96) ----
// thread = (chunk c, node i, quad-col q); one 8-B load per neighbor, 2.4 MB working set
#define AGGT (NCH * NN * 6)   // 1,200,000
__global__ void k_agg(const unsigned short* __restrict__ hp_c,
                      const int* __restrict__ cnt, const int* __restrict__ off,
                      const int* __restrict__ csr, const float* __restrict__ dinv,
                      const float* __restrict__ bg,
                      unsigned short* __restrict__ zb) {
    int t = blockIdx.x * 256 + threadIdx.x;
    if (t >= AGGT) return;
    int c = t / (NN * 6);
    int rem = t - c * (NN * 6);
    int i = rem / 6;
    int q = rem - i * 6;                 // 4-col group within chunk
    const unsigned short* base = hp_c + (size_t)c * NN * CW + q * 4;

    ushort4 sv = *(const ushort4*)(base + (size_t)i * CW);  // self-loop term
    float a0 = bu2f(sv.x), a1 = bu2f(sv.y), a2 = bu2f(sv.z), a3 = bu2f(sv.w);

    int idx = off[i];
    const int cdeg = cnt[i];
    const int end = idx + cdeg;
    for (; idx + 1 < end; idx += 2) {
        int s0 = csr[idx], s1 = csr[idx + 1];
        ushort4 v0 = *(const ushort4*)(base + (size_t)s0 * CW);
        ushort4 v1 = *(const ushort4*)(base + (size_t)s1 * CW);
        a0 += bu2f(v0.x) + bu2f(v1.x);
        a1 += bu2f(v0.y) + bu2f(v1.y);
        a2 += bu2f(v0.z) + bu2f(v1.z);
        a3 += bu2f(v0.w) + bu2f(v1.w);
    }
    if (idx < end) {
        ushort4 v0 = *(const ushort4*)(base + (size_t)csr[idx] * CW);
        a0 += bu2f(v0.x); a1 += bu2f(v0.y); a2 += bu2f(v0.z); a3 += bu2f(v0.w);
    }
    const float dv = dinv[i];
    const int j = c * CW + q * 4;
    ushort4 o;
    o.x = f2bu(fmaxf(fmaf(dv, a0, bg[j + 0]), 0.f));
    o.y = f2bu(fmaxf(fmaf(dv, a1, bg[j + 1]), 0.f));
    o.z = f2bu(fmaxf(fmaf(dv, a2, bg[j + 2]), 0.f));
    o.w = f2bu(fmaxf(fmaf(dv, a3, bg[j + 3]), 0.f));
    *(ushort4*)(zb + (size_t)i * ZK + j) = o;
}

// ---- kernel 7b: zb tail — temporal cols [96,128) for all rows; zero pad rows ----
#define ZTA (NPAD * 32)                 // col-tail elements
#define ZTB ((NPAD - NN) * HH)          // pad-row elements (cols 0..96)
__global__ void k_ztail(const float* __restrict__ tmp, unsigned short* __restrict__ zb) {
    int t = blockIdx.x * 256 + threadIdx.x;
    if (t < ZTA) {
        int i = t >> 5, cc = t & 31;
        unsigned short v = 0;
        if (i < NN && cc < TF) v = f2bu(tmp[(size_t)i * TF + cc]);
        zb[(size_t)i * ZK + HH + cc] = v;
    } else {
        int u = t - ZTA;
        if (u < ZTB) {
            int i = NN + u / HH, j = u % HH;
            zb[(size_t)i * ZK + j] = 0;
        }
    }
}

// ---- kernel 8: MFMA layer-1 + fused layer-2 dot epilogue ----
__global__ __launch_bounds__(256) void k_mlp2(const unsigned short* __restrict__ zb,
                                              const unsigned short* __restrict__ Wt1,
                                              const float* __restrict__ b1,
                                              const float* __restrict__ W2,
                                              const float* __restrict__ b2,
                                              const float* __restrict__ x,
                                              float* __restrict__ out) {
    const int wave = threadIdx.x >> 6;
    const int lane = threadIdx.x & 63;
    const int quad = lane >> 4;
    const int l16 = lane & 15;
    const int Mbase = blockIdx.x * 64 + wave * 16;

    const unsigned short* arow = zb + (size_t)(Mbase + l16) * ZK + quad * 8;
    const unsigned short* brow = Wt1 + (size_t)l16 * ZK + quad * 8;

    f32x4 acc[6] = {};
#pragma unroll
    for (int ks = 0; ks < 4; ++ks) {
        short8 a = *(const short8*)(arow + ks * 32);
#pragma unroll
        for (int nt = 0; nt < 6; ++nt) {
            short8 bfrag = *(const short8*)(brow + (size_t)nt * 16 * ZK + ks * 32);
            acc[nt] = __builtin_amdgcn_mfma_f32_16x16x32_bf16(a, bfrag, acc[nt], 0, 0, 0);
        }
    }
    float bb[6], wa[6];
#pragma unroll
    for (int nt = 0; nt < 6; ++nt) {
        int c = nt * 16 + l16;
        bb[nt] = b1[c];
        wa[nt] = W2[c];
    }
    float wx[8];
#pragma unroll
    for (int m = 0; m < 8; ++m) wx[m] = W2[HH + l16 * 8 + m];
    const float bias2 = b2[0];

#pragma unroll
    for (int reg = 0; reg < 4; ++reg) {
        const int r = Mbase + quad * 4 + reg;
        float p = 0.f;
#pragma unroll
        for (int nt = 0; nt < 6; ++nt)
            p = fmaf(fmaxf(acc[nt][reg] + bb[nt], 0.f), wa[nt], p);
        if (r < NN) {
            const float4 xa = *(const float4*)(x + (size_t)r * NF + l16 * 8);
            const float4 xc = *(const float4*)(x + (size_t)r * NF + l16 * 8 + 4);
            p = fmaf(xa.x, wx[0], p); p = fmaf(xa.y, wx[1], p);
            p = fmaf(xa.z, wx[2], p); p = fmaf(xa.w, wx[3], p);
            p = fmaf(xc.x, wx[4], p); p = fmaf(xc.y, wx[5], p);
            p = fmaf(xc.z, wx[6], p); p = fmaf(xc.w, wx[7], p);
        }
#pragma unroll
        for (int m = 1; m < 16; m <<= 1) p += __shfl_xor(p, m, 64);
        if (l16 == 0 && r < NN) out[r] = fmaxf(p + bias2, 0.f);
    }
}

extern "C" void kernel_launch(void* const* d_in, const int* in_sizes, int n_in,
                              void* d_out, int out_size, void* d_ws, size_t ws_size,
                              hipStream_t stream) {
    const float* x   = (const float*)d_in[0];
    const int*   ei  = (const int*)d_in[1];
    const float* tmp = (const float*)d_in[2];
    const float* Wg  = (const float*)d_in[3];
    const float* bg  = (const float*)d_in[4];
    const float* W1  = (const float*)d_in[5];
    const float* b1  = (const float*)d_in[6];
    const float* W2  = (const float*)d_in[7];
    const float* b2  = (const float*)d_in[8];
    float* out = (float*)d_out;

    char* base = (char*)d_ws;
    int* cnt = (int*)base;                 // 65536 ints
    int* cur = cnt + 65536;
    int* off = cur + 65536;
    int* csr = off + 65536;                // NE ints
    int* bsum = csr + NE;                  // NB ints
    int* bbase = bsum + 256;               // NB+1 ints (all < 4 MiB)
    float* dinv = (float*)(base + ((size_t)4 << 20));            // 65536 floats
    unsigned short* xb = (unsigned short*)(base + ((size_t)4 << 20) + 262144);  // NPAD*NF bf16
    unsigned short* Wt = xb + (size_t)NPAD * NF;                 // NF*HH bf16
    unsigned short* hp_c = Wt + NF * HH;                         // NN*HH bf16 (chunked)
    unsigned short* Wt1 = hp_c + (size_t)NN * HH;                // HH*ZK bf16
    unsigned short* zb = Wt1 + HH * ZK;                          // NPAD*ZK bf16

    k_zero <<<(NN + 255) / 256, 256, 0, stream>>>(cnt, cur);
    k_count<<<(NE + 255) / 256, 256, 0, stream>>>(ei + NE, cnt);
    k_bsum <<<NB, 256, 0, stream>>>(cnt, bsum);
    k_bscan<<<1, 256, 0, stream>>>(bsum, bbase);
    k_off  <<<NB, 256, 0, stream>>>(cnt, bbase, off, dinv);
    k_fill <<<(NE + 255) / 256, 256, 0, stream>>>(ei, off, cur, csr);
    k_prep <<<XBLK + WBLK + W1BLK, 256, 0, stream>>>(x, Wg, W1, xb, Wt, Wt1);
    k_gemm <<<NPAD / 64, 256, 0, stream>>>(xb, Wt, dinv, hp_c);
    k_agg  <<<(AGGT + 255) / 256, 256, 0, stream>>>(hp_c, cnt, off, csr, dinv, bg, zb);
    k_ztail<<<(ZTA + ZTB + 255) / 256, 256, 0, stream>>>(tmp, zb);
    k_mlp2 <<<NPAD / 64, 256, 0, stream>>>(zb, Wt1, b1, W2, b2, x, out);
}

// Round 9
// 208.905 us; speedup vs baseline: 7.4222x; 1.2557x over previous
//
#include <hip/hip_runtime.h>
#include <hip/hip_bf16.h>

#define NN 50000
#define NPAD 50048           // 64-row padded for MFMA grid
#define NE 800000
#define NF 128
#define HH 96
#define TF 10
#define Z1DIM (HH + TF)   // 106
#define ZK 128            // padded K for layer-1 MFMA
#define NCH 4             // column chunks for the gather
#define CW 24             // chunk width (cols): NCH*CW == HH
#define NBK 196           // dst buckets of 256 nodes
#define CAP 5120          // per-bucket temp capacity (mean 4096, +16 sigma)
#define EPB 8192          // edges per k_fillA block

typedef __attribute__((ext_vector_type(8))) short short8;
typedef __attribute__((ext_vector_type(4))) float f32x4;

__device__ __forceinline__ float bu2f(unsigned short u) {
    union { unsigned int i; float f; } c;
    c.i = ((unsigned int)u) << 16;
    return c.f;
}
__device__ __forceinline__ unsigned short f2bu(float f) {
    union { __hip_bfloat16 h; unsigned short u; } c;
    c.h = __float2bfloat16(f);
    return c.u;
}

// ---- kernel 1: bcur[b] = b*CAP ----
__global__ void k_init(int* __restrict__ bcur) {
    int t = threadIdx.x;
    if (t < NBK) bcur[t] = t * CAP;
}

// ---- kernel 2: bin edges into 196 dst-range buckets (counting-sort pass 1) ----
__global__ __launch_bounds__(256) void k_fillA(const int* __restrict__ ei,
                                               int* __restrict__ bcur,
                                               int* __restrict__ temp) {
    __shared__ int hist[NBK], base[NBK];
    const int t = threadIdx.x;
    for (int m = t; m < NBK; m += 256) hist[m] = 0;
    __syncthreads();
    const int e0 = blockIdx.x * EPB;
    const int ecap = min(e0 + EPB, NE);
    for (int e = e0 + t; e < ecap; e += 256) {
        int d = ei[NE + e];
        atomicAdd(&hist[d >> 8], 1);
    }
    __syncthreads();
    for (int m = t; m < NBK; m += 256) {
        int c = hist[m];
        base[m] = c ? atomicAdd(&bcur[m], c) : 0;
        hist[m] = 0;   // reuse as run cursor
    }
    __syncthreads();
    for (int e = e0 + t; e < ecap; e += 256) {
        int d = ei[NE + e], s = ei[e];
        int b = d >> 8;
        int r = atomicAdd(&hist[b], 1);
        temp[base[b] + r] = ((d & 255) << 16) | s;
    }
}

// ---- kernel 3: exclusive scan of bucket sizes -> gbase ----
__global__ __launch_bounds__(256) void k_gscan(const int* __restrict__ bcur,
                                               int* __restrict__ gbase) {
    __shared__ int p[256];
    const int t = threadIdx.x;
    int sz = (t < NBK) ? (bcur[t] - t * CAP) : 0;
    p[t] = sz;
    __syncthreads();
#pragma unroll
    for (int d = 1; d < 256; d <<= 1) {
        int u = (t >= d) ? p[t - d] : 0;
        __syncthreads();
        p[t] += u;
        __syncthreads();
    }
    if (t < NBK) gbase[t] = p[t] - sz;
}

// ---- kernel 4: per-bucket local sort -> csr, cnt, off, dinv (counting-sort pass 2) ----
__global__ __launch_bounds__(256) void k_fillB(const int* __restrict__ temp,
                                               const int* __restrict__ bcur,
                                               const int* __restrict__ gbase,
                                               int* __restrict__ csr,
                                               int* __restrict__ cnt,
                                               int* __restrict__ off,
                                               float* __restrict__ dinv) {
    __shared__ int ls[256], lc[256];
    const int b = blockIdx.x, t = threadIdx.x;
    const int seg0 = b * CAP;
    const int m = bcur[b] - seg0;
    const int g0 = gbase[b];
    ls[t] = 0;
    __syncthreads();
    for (int k = t; k < m; k += 256) atomicAdd(&ls[temp[seg0 + k] >> 16], 1);
    __syncthreads();
    const int myc = ls[t];
    lc[t] = myc;
    __syncthreads();
#pragma unroll
    for (int d = 1; d < 256; d <<= 1) {
        int u = (t >= d) ? lc[t - d] : 0;
        __syncthreads();
        lc[t] += u;
        __syncthreads();
    }
    const int myoff = lc[t] - myc;    // exclusive within bucket
    __syncthreads();
    lc[t] = myoff;                    // cursor
    const int i = b * 256 + t;
    if (i < NN) {
        cnt[i] = myc;
        off[i] = g0 + myoff;
        dinv[i] = rsqrtf((float)myc + 1.0f);
    }
    __syncthreads();
    for (int k = t; k < m; k += 256) {
        int v = temp[seg0 + k];
        int r = atomicAdd(&lc[v >> 16], 1);
        csr[g0 + r] = v & 0xFFFF;
    }
}

// ---- kernel 5: prep — xb = bf16(x) padded; Wt = bf16(Wg)^T; Wt1 = bf16(W1)^T K-padded ----
#define XBLK (NPAD * NF / 4 / 256)     // 6256
#define WBLK (NF * HH / 4 / 256)       // 12
#define W1BLK (HH * ZK / 4 / 256)      // 12
__global__ void k_prep(const float* __restrict__ x, const float* __restrict__ W,
                       const float* __restrict__ W1,
                       unsigned short* __restrict__ xb, unsigned short* __restrict__ Wt,
                       unsigned short* __restrict__ Wt1) {
    int b = blockIdx.x;
    if (b < XBLK) {
        int idx4 = (b * 256 + threadIdx.x) * 4;
        int row = idx4 >> 7;
        ushort4 v;
        if (row < NN) {
            float4 f = *(const float4*)(x + idx4);
            v.x = f2bu(f.x); v.y = f2bu(f.y); v.z = f2bu(f.z); v.w = f2bu(f.w);
        } else {
            v.x = v.y = v.z = v.w = 0;
        }
        *(ushort4*)(xb + idx4) = v;
    } else if (b < XBLK + WBLK) {
        int e = ((b - XBLK) * 256 + threadIdx.x) * 4;
        int n = e >> 7, k = e & 127;
        ushort4 v;
        v.x = f2bu(W[(k + 0) * HH + n]);
        v.y = f2bu(W[(k + 1) * HH + n]);
        v.z = f2bu(W[(k + 2) * HH + n]);
        v.w = f2bu(W[(k + 3) * HH + n]);
        *(ushort4*)(Wt + e) = v;
    } else {
        int e = ((b - XBLK - WBLK) * 256 + threadIdx.x) * 4;
        int n = e >> 7, k = e & 127;     // n in [0,96), k in [0,128)
        ushort4 v;
        v.x = (k + 0 < Z1DIM) ? f2bu(W1[(k + 0) * HH + n]) : (unsigned short)0;
        v.y = (k + 1 < Z1DIM) ? f2bu(W1[(k + 1) * HH + n]) : (unsigned short)0;
        v.z = (k + 2 < Z1DIM) ? f2bu(W1[(k + 2) * HH + n]) : (unsigned short)0;
        v.w = (k + 3 < Z1DIM) ? f2bu(W1[(k + 3) * HH + n]) : (unsigned short)0;
        *(ushort4*)(Wt1 + e) = v;
    }
}

// ---- kernel 6: MFMA GEMM. hp_c[chunk][row][24] = bf16( (x @ Wg) * dinv[row] ) ----
__global__ __launch_bounds__(256) void k_gemm(const unsigned short* __restrict__ xb,
                                              const unsigned short* __restrict__ Wt,
                                              const float* __restrict__ dinv,
                                              unsigned short* __restrict__ hp_c) {
    const int wave = threadIdx.x >> 6;
    const int lane = threadIdx.x & 63;
    const int quad = lane >> 4;
    const int l16 = lane & 15;
    const int Mbase = blockIdx.x * 64 + wave * 16;

    const unsigned short* arow = xb + (size_t)(Mbase + l16) * NF + quad * 8;
    const unsigned short* brow = Wt + (size_t)l16 * NF + quad * 8;

    f32x4 acc[6] = {};
#pragma unroll
    for (int ks = 0; ks < 4; ++ks) {
        short8 a = *(const short8*)(arow + ks * 32);
#pragma unroll
        for (int nt = 0; nt < 6; ++nt) {
            short8 bfrag = *(const short8*)(brow + (size_t)nt * 16 * NF + ks * 32);
            acc[nt] = __builtin_amdgcn_mfma_f32_16x16x32_bf16(a, bfrag, acc[nt], 0, 0, 0);
        }
    }
    const int r0 = Mbase + quad * 4;
    float dv0 = (r0 + 0 < NN) ? dinv[r0 + 0] : 0.f;
    float dv1 = (r0 + 1 < NN) ? dinv[r0 + 1] : 0.f;
    float dv2 = (r0 + 2 < NN) ? dinv[r0 + 2] : 0.f;
    float dv3 = (r0 + 3 < NN) ? dinv[r0 + 3] : 0.f;
#pragma unroll
    for (int nt = 0; nt < 6; ++nt) {
        int n = nt * 16 + l16;
        int c = n / CW, jj = n - c * CW;
        unsigned short* dst = hp_c + (size_t)c * NN * CW + jj;
        if (r0 + 0 < NN) dst[(size_t)(r0 + 0) * CW] = f2bu(acc[nt][0] * dv0);
        if (r0 + 1 < NN) dst[(size_t)(r0 + 1) * CW] = f2bu(acc[nt][1] * dv1);
        if (r0 + 2 < NN) dst[(size_t)(r0 + 2) * CW] = f2bu(acc[nt][2] * dv2);
        if (r0 + 3 < NN) dst[(size_t)(r0 + 3) * CW] = f2bu(acc[nt][3] * dv3);
    }
}

// ---- kernel 7: chunked gather-aggregate -> zb[i][0..96) ----
#define AGGT (NCH * NN * 6)   // 1,200,000
__global__ void k_agg(const unsigned short* __restrict__ hp_c,
                      const int* __restrict__ cnt, const int* __restrict__ off,
                      const int* __restrict__ csr, const float* __restrict__ dinv,
                      const float* __restrict__ bg,
                      unsigned short* __restrict__ zb) {
    int t = blockIdx.x * 256 + threadIdx.x;
    if (t >= AGGT) return;
    int c = t / (NN * 6);
    int rem = t - c * (NN * 6);
    int i = rem / 6;
    int q = rem - i * 6;                 // 4-col group within chunk
    const unsigned short* base = hp_c + (size_t)c * NN * CW + q * 4;

    ushort4 sv = *(const ushort4*)(base + (size_t)i * CW);  // self-loop term
    float a0 = bu2f(sv.x), a1 = bu2f(sv.y), a2 = bu2f(sv.z), a3 = bu2f(sv.w);

    int idx = off[i];
    const int cdeg = cnt[i];
    const int end = idx + cdeg;
    for (; idx + 1 < end; idx += 2) {
        int s0 = csr[idx], s1 = csr[idx + 1];
        ushort4 v0 = *(const ushort4*)(base + (size_t)s0 * CW);
        ushort4 v1 = *(const ushort4*)(base + (size_t)s1 * CW);
        a0 += bu2f(v0.x) + bu2f(v1.x);
        a1 += bu2f(v0.y) + bu2f(v1.y);
        a2 += bu2f(v0.z) + bu2f(v1.z);
        a3 += bu2f(v0.w) + bu2f(v1.w);
    }
    if (idx < end) {
        ushort4 v0 = *(const ushort4*)(base + (size_t)csr[idx] * CW);
        a0 += bu2f(v0.x); a1 += bu2f(v0.y); a2 += bu2f(v0.z); a3 += bu2f(v0.w);
    }
    const float dv = dinv[i];
    const int j = c * CW + q * 4;
    ushort4 o;
    o.x = f2bu(fmaxf(fmaf(dv, a0, bg[j + 0]), 0.f));
    o.y = f2bu(fmaxf(fmaf(dv, a1, bg[j + 1]), 0.f));
    o.z = f2bu(fmaxf(fmaf(dv, a2, bg[j + 2]), 0.f));
    o.w = f2bu(fmaxf(fmaf(dv, a3, bg[j + 3]), 0.f));
    *(ushort4*)(zb + (size_t)i * ZK + j) = o;
}

// ---- kernel 7b: zb tail — temporal cols [96,128) for all rows; zero pad rows ----
#define ZTA (NPAD * 32)                 // col-tail elements
#define ZTB ((NPAD - NN) * HH)          // pad-row elements (cols 0..96)
__global__ void k_ztail(const float* __restrict__ tmp, unsigned short* __restrict__ zb) {
    int t = blockIdx.x * 256 + threadIdx.x;
    if (t < ZTA) {
        int i = t >> 5, cc = t & 31;
        unsigned short v = 0;
        if (i < NN && cc < TF) v = f2bu(tmp[(size_t)i * TF + cc]);
        zb[(size_t)i * ZK + HH + cc] = v;
    } else {
        int u = t - ZTA;
        if (u < ZTB) {
            int i = NN + u / HH, j = u % HH;
            zb[(size_t)i * ZK + j] = 0;
        }
    }
}

// ---- kernel 8: MFMA layer-1 + fused layer-2 dot epilogue ----
__global__ __launch_bounds__(256) void k_mlp2(const unsigned short* __restrict__ zb,
                                              const unsigned short* __restrict__ Wt1,
                                              const float* __restrict__ b1,
                                              const float* __restrict__ W2,
                                              const float* __restrict__ b2,
                                              const float* __restrict__ x,
                                              float* __restrict__ out) {
    const int wave = threadIdx.x >> 6;
    const int lane = threadIdx.x & 63;
    const int quad = lane >> 4;
    const int l16 = lane & 15;
    const int Mbase = blockIdx.x * 64 + wave * 16;

    const unsigned short* arow = zb + (size_t)(Mbase + l16) * ZK + quad * 8;
    const unsigned short* brow = Wt1 + (size_t)l16 * ZK + quad * 8;

    f32x4 acc[6] = {};
#pragma unroll
    for (int ks = 0; ks < 4; ++ks) {
        short8 a = *(const short8*)(arow + ks * 32);
#pragma unroll
        for (int nt = 0; nt < 6; ++nt) {
            short8 bfrag = *(const short8*)(brow + (size_t)nt * 16 * ZK + ks * 32);
            acc[nt] = __builtin_amdgcn_mfma_f32_16x16x32_bf16(a, bfrag, acc[nt], 0, 0, 0);
        }
    }
    float bb[6], wa[6];
#pragma unroll
    for (int nt = 0; nt < 6; ++nt) {
        int c = nt * 16 + l16;
        bb[nt] = b1[c];
        wa[nt] = W2[c];
    }
    float wx[8];
#pragma unroll
    for (int m = 0; m < 8; ++m) wx[m] = W2[HH + l16 * 8 + m];
    const float bias2 = b2[0];

#pragma unroll
    for (int reg = 0; reg < 4; ++reg) {
        const int r = Mbase + quad * 4 + reg;
        float p = 0.f;
#pragma unroll
        for (int nt = 0; nt < 6; ++nt)
            p = fmaf(fmaxf(acc[nt][reg] + bb[nt], 0.f), wa[nt], p);
        if (r < NN) {
            const float4 xa = *(const float4*)(x + (size_t)r * NF + l16 * 8);
            const float4 xc = *(const float4*)(x + (size_t)r * NF + l16 * 8 + 4);
            p = fmaf(xa.x, wx[0], p); p = fmaf(xa.y, wx[1], p);
            p = fmaf(xa.z, wx[2], p); p = fmaf(xa.w, wx[3], p);
            p = fmaf(xc.x, wx[4], p); p = fmaf(xc.y, wx[5], p);
            p = fmaf(xc.z, wx[6], p); p = fmaf(xc.w, wx[7], p);
        }
#pragma unroll
        for (int m = 1; m < 16; m <<= 1) p += __shfl_xor(p, m, 64);
        if (l16 == 0 && r < NN) out[r] = fmaxf(p + bias2, 0.f);
    }
}

extern "C" void kernel_launch(void* const* d_in, const int* in_sizes, int n_in,
                              void* d_out, int out_size, void* d_ws, size_t ws_size,
                              hipStream_t stream) {
    const float* x   = (const float*)d_in[0];
    const int*   ei  = (const int*)d_in[1];
    const float* tmp = (const float*)d_in[2];
    const float* Wg  = (const float*)d_in[3];
    const float* bg  = (const float*)d_in[4];
    const float* W1  = (const float*)d_in[5];
    const float* b1  = (const float*)d_in[6];
    const float* W2  = (const float*)d_in[7];
    const float* b2  = (const float*)d_in[8];
    float* out = (float*)d_out;

    char* base = (char*)d_ws;
    int* cnt  = (int*)base;                // 65536 ints
    int* off  = cnt + 65536;               // 65536 ints
    int* bcur = off + 65536;               // 256 ints
    int* gbase = bcur + 256;               // 256 ints
    int* csr  = gbase + 256;               // NE ints; all < 4 MiB
    float* dinv = (float*)(base + ((size_t)4 << 20));            // 65536 floats
    unsigned short* xb = (unsigned short*)(base + ((size_t)4 << 20) + 262144);  // NPAD*NF bf16
    unsigned short* Wt = xb + (size_t)NPAD * NF;                 // NF*HH bf16
    unsigned short* hp_c = Wt + NF * HH;                         // NN*HH bf16 (chunked)
    unsigned short* Wt1 = hp_c + (size_t)NN * HH;                // HH*ZK bf16
    unsigned short* zb = Wt1 + HH * ZK;                          // NPAD*ZK bf16
    int* temp = (int*)zb;   // 196*5120 ints = 4.01 MB, aliases zb (consumed before zb written)

    k_init <<<1, 256, 0, stream>>>(bcur);
    k_fillA<<<(NE + EPB - 1) / EPB, 256, 0, stream>>>(ei, bcur, temp);
    k_gscan<<<1, 256, 0, stream>>>(bcur, gbase);
    k_fillB<<<NBK, 256, 0, stream>>>(temp, bcur, gbase, csr, cnt, off, dinv);
    k_prep <<<XBLK + WBLK + W1BLK, 256, 0, stream>>>(x, Wg, W1, xb, Wt, Wt1);
    k_gemm <<<NPAD / 64, 256, 0, stream>>>(xb, Wt, dinv, hp_c);
    k_agg  <<<(AGGT + 255) / 256, 256, 0, stream>>>(hp_c, cnt, off, csr, dinv, bg, zb);
    k_ztail<<<(ZTA + ZTB + 255) / 256, 256, 0, stream>>>(tmp, zb);
    k_mlp2 <<<NPAD / 64, 256, 0, stream>>>(zb, Wt1, b1, W2, b2, x, out);
}

// Round 10
// 195.255 us; speedup vs baseline: 7.9411x; 1.0699x over previous
//
#include <hip/hip_runtime.h>
#include <hip/hip_bf16.h>

#define NN 50000
#define NPAD 50048           // 64-row padded for MFMA grid
#define NE 800000
#define NF 128
#define HH 96
#define TF 10
#define Z1DIM (HH + TF)   // 106
#define ZK 128            // padded K for layer-1 MFMA
#define NCH 4             // column chunks for the gather
#define CW 24             // chunk width (cols): NCH*CW == HH
#define NBK 196           // dst buckets of 256 nodes
#define CAP 5120          // per-bucket temp capacity
#define EPB 8192          // edges per k_fillA block

typedef __attribute__((ext_vector_type(8))) short short8;
typedef __attribute__((ext_vector_type(8))) unsigned short ushort8;
typedef __attribute__((ext_vector_type(4))) float f32x4;

__device__ __forceinline__ float bu2f(unsigned short u) {
    union { unsigned int i; float f; } c;
    c.i = ((unsigned int)u) << 16;
    return c.f;
}
__device__ __forceinline__ unsigned short f2bu(float f) {
    union { __hip_bfloat16 h; unsigned short u; } c;
    c.h = __float2bfloat16(f);
    return c.u;
}

// ---- kernel 1: bcur[b] = b*CAP; off[NN] = NE ----
__global__ void k_init(int* __restrict__ bcur, int* __restrict__ off) {
    int t = threadIdx.x;
    if (t < NBK) bcur[t] = t * CAP;
    if (t == 255) off[NN] = NE;
}

// ---- kernel 2: bin edges into 196 dst-range buckets (counting-sort pass 1) ----
__global__ __launch_bounds__(256) void k_fillA(const int* __restrict__ ei,
                                               int* __restrict__ bcur,
                                               int* __restrict__ temp) {
    __shared__ int hist[NBK], base[NBK];
    const int t = threadIdx.x;
    for (int m = t; m < NBK; m += 256) hist[m] = 0;
    __syncthreads();
    const int e0 = blockIdx.x * EPB;
    const int ecap = min(e0 + EPB, NE);
    for (int e = e0 + t; e < ecap; e += 256) {
        int d = ei[NE + e];
        atomicAdd(&hist[d >> 8], 1);
    }
    __syncthreads();
    for (int m = t; m < NBK; m += 256) {
        int c = hist[m];
        base[m] = c ? atomicAdd(&bcur[m], c) : 0;
        hist[m] = 0;   // reuse as run cursor
    }
    __syncthreads();
    for (int e = e0 + t; e < ecap; e += 256) {
        int d = ei[NE + e], s = ei[e];
        int b = d >> 8;
        int r = atomicAdd(&hist[b], 1);
        temp[base[b] + r] = ((d & 255) << 16) | s;
    }
}

// ---- kernel 3: exclusive scan of bucket sizes -> gbase ----
__global__ __launch_bounds__(256) void k_gscan(const int* __restrict__ bcur,
                                               int* __restrict__ gbase) {
    __shared__ int p[256];
    const int t = threadIdx.x;
    int sz = (t < NBK) ? (bcur[t] - t * CAP) : 0;
    p[t] = sz;
    __syncthreads();
#pragma unroll
    for (int d = 1; d < 256; d <<= 1) {
        int u = (t >= d) ? p[t - d] : 0;
        __syncthreads();
        p[t] += u;
        __syncthreads();
    }
    if (t < NBK) gbase[t] = p[t] - sz;
}

// ---- kernel 4: per-bucket local sort -> csr, off (counting-sort pass 2) ----
__global__ __launch_bounds__(256) void k_fillB(const int* __restrict__ temp,
                                               const int* __restrict__ bcur,
                                               const int* __restrict__ gbase,
                                               int* __restrict__ csr,
                                               int* __restrict__ off) {
    __shared__ int ls[256], lc[256];
    const int b = blockIdx.x, t = threadIdx.x;
    const int seg0 = b * CAP;
    const int m = bcur[b] - seg0;
    const int g0 = gbase[b];
    ls[t] = 0;
    __syncthreads();
    for (int k = t; k < m; k += 256) atomicAdd(&ls[temp[seg0 + k] >> 16], 1);
    __syncthreads();
    const int myc = ls[t];
    lc[t] = myc;
    __syncthreads();
#pragma unroll
    for (int d = 1; d < 256; d <<= 1) {
        int u = (t >= d) ? lc[t - d] : 0;
        __syncthreads();
        lc[t] += u;
        __syncthreads();
    }
    const int myoff = lc[t] - myc;    // exclusive within bucket
    __syncthreads();
    lc[t] = myoff;                    // cursor
    const int i = b * 256 + t;
    if (i < NN) off[i] = g0 + myoff;
    __syncthreads();
    for (int k = t; k < m; k += 256) {
        int v = temp[seg0 + k];
        int r = atomicAdd(&lc[v >> 16], 1);
        csr[g0 + r] = v & 0xFFFF;
    }
}

// ---- kernel 5: prep — xb, Wt, Wt1, and zb tail (cols 96..128 + pad rows) ----
#define XBLK (NPAD * NF / 4 / 256)     // 6256
#define WBLK (NF * HH / 4 / 256)       // 12
#define W1BLK (HH * ZK / 4 / 256)      // 12
#define ZTBLK (NPAD / 32)              // 1564 : NPAD*32 elems / 4 / 256
#define ZPBLK 5                        // (NPAD-NN)*HH = 4608 elems / 4 / 256 -> 4.5
__global__ void k_prep(const float* __restrict__ x, const float* __restrict__ W,
                       const float* __restrict__ W1, const float* __restrict__ tmp,
                       unsigned short* __restrict__ xb, unsigned short* __restrict__ Wt,
                       unsigned short* __restrict__ Wt1, unsigned short* __restrict__ zb) {
    int b = blockIdx.x;
    if (b < XBLK) {
        int idx4 = (b * 256 + threadIdx.x) * 4;
        int row = idx4 >> 7;
        ushort4 v;
        if (row < NN) {
            float4 f = *(const float4*)(x + idx4);
            v.x = f2bu(f.x); v.y = f2bu(f.y); v.z = f2bu(f.z); v.w = f2bu(f.w);
        } else {
            v.x = v.y = v.z = v.w = 0;
        }
        *(ushort4*)(xb + idx4) = v;
    } else if (b < XBLK + WBLK) {
        int e = ((b - XBLK) * 256 + threadIdx.x) * 4;
        int n = e >> 7, k = e & 127;
        ushort4 v;
        v.x = f2bu(W[(k + 0) * HH + n]);
        v.y = f2bu(W[(k + 1) * HH + n]);
        v.z = f2bu(W[(k + 2) * HH + n]);
        v.w = f2bu(W[(k + 3) * HH + n]);
        *(ushort4*)(Wt + e) = v;
    } else if (b < XBLK + WBLK + W1BLK) {
        int e = ((b - XBLK - WBLK) * 256 + threadIdx.x) * 4;
        int n = e >> 7, k = e & 127;     // n in [0,96), k in [0,128)
        ushort4 v;
        v.x = (k + 0 < Z1DIM) ? f2bu(W1[(k + 0) * HH + n]) : (unsigned short)0;
        v.y = (k + 1 < Z1DIM) ? f2bu(W1[(k + 1) * HH + n]) : (unsigned short)0;
        v.z = (k + 2 < Z1DIM) ? f2bu(W1[(k + 2) * HH + n]) : (unsigned short)0;
        v.w = (k + 3 < Z1DIM) ? f2bu(W1[(k + 3) * HH + n]) : (unsigned short)0;
        *(ushort4*)(Wt1 + e) = v;
    } else if (b < XBLK + WBLK + W1BLK + ZTBLK) {
        // zb cols [96,128): temporal (cc<10) else 0; pad rows all-zero here too
        int t4 = ((b - XBLK - WBLK - W1BLK) * 256 + threadIdx.x) * 4;
        int i = t4 >> 5, cc = t4 & 31;
        ushort4 v; v.x = v.y = v.z = v.w = 0;
        if (i < NN) {
            if (cc + 0 < TF) v.x = f2bu(tmp[(size_t)i * TF + cc + 0]);
            if (cc + 1 < TF) v.y = f2bu(tmp[(size_t)i * TF + cc + 1]);
            if (cc + 2 < TF) v.z = f2bu(tmp[(size_t)i * TF + cc + 2]);
            if (cc + 3 < TF) v.w = f2bu(tmp[(size_t)i * TF + cc + 3]);
        }
        *(ushort4*)(zb + (size_t)i * ZK + HH + cc) = v;
    } else {
        // zb pad rows [NN,NPAD), cols [0,96): zero
        int t4 = ((b - XBLK - WBLK - W1BLK - ZTBLK) * 256 + threadIdx.x) * 4;
        if (t4 < (NPAD - NN) * HH) {
            int i = NN + t4 / HH, j = t4 % HH;
            ushort4 z; z.x = z.y = z.z = z.w = 0;
            *(ushort4*)(zb + (size_t)i * ZK + j) = z;
        }
    }
}

// ---- kernel 6: MFMA GEMM. hp_c[chunk][row][24] = bf16( (x @ Wg) * dinv[row] ) ----
__global__ __launch_bounds__(256) void k_gemm(const unsigned short* __restrict__ xb,
                                              const unsigned short* __restrict__ Wt,
                                              const int* __restrict__ off,
                                              unsigned short* __restrict__ hp_c) {
    const int wave = threadIdx.x >> 6;
    const int lane = threadIdx.x & 63;
    const int quad = lane >> 4;
    const int l16 = lane & 15;
    const int Mbase = blockIdx.x * 64 + wave * 16;

    const unsigned short* arow = xb + (size_t)(Mbase + l16) * NF + quad * 8;
    const unsigned short* brow = Wt + (size_t)l16 * NF + quad * 8;

    f32x4 acc[6] = {};
#pragma unroll
    for (int ks = 0; ks < 4; ++ks) {
        short8 a = *(const short8*)(arow + ks * 32);
#pragma unroll
        for (int nt = 0; nt < 6; ++nt) {
            short8 bfrag = *(const short8*)(brow + (size_t)nt * 16 * NF + ks * 32);
            acc[nt] = __builtin_amdgcn_mfma_f32_16x16x32_bf16(a, bfrag, acc[nt], 0, 0, 0);
        }
    }
    const int r0 = Mbase + quad * 4;
    float dv[4];
#pragma unroll
    for (int k = 0; k < 4; ++k) {
        int r = r0 + k;
        dv[k] = (r < NN) ? rsqrtf((float)(off[r + 1] - off[r]) + 1.f) : 0.f;
    }
#pragma unroll
    for (int nt = 0; nt < 6; ++nt) {
        int n = nt * 16 + l16;
        int c = n / CW, jj = n - c * CW;
        unsigned short* dst = hp_c + (size_t)c * NN * CW + jj;
#pragma unroll
        for (int k = 0; k < 4; ++k)
            if (r0 + k < NN) dst[(size_t)(r0 + k) * CW] = f2bu(acc[nt][k] * dv[k]);
    }
}

// ---- kernel 7: chunked gather-aggregate -> zb[i][0..96), XCD-affine ----
// block decode: slot=b&7 -> chunk=slot>>1, half=slot&1 (pins each 2.4MB slice to 2 XCDs)
// thread = (node i, 8-col group q): one 16-B load per neighbor
#define RPC 586                 // 256-thread rows per chunk: NN*3/256 rounded up
#define AGGB (4 * RPC)          // 2344 blocks total (RPC even-split: 293*8)
__global__ __launch_bounds__(256) void k_agg(const unsigned short* __restrict__ hp_c,
                                             const int* __restrict__ off,
                                             const int* __restrict__ csr,
                                             const float* __restrict__ bg,
                                             unsigned short* __restrict__ zb) {
    const int b = blockIdx.x;
    const int slot = b & 7;
    const int c = slot >> 1;
    const int r = (b >> 3) * 2 + (slot & 1);       // 0..585
    const int item = r * 256 + threadIdx.x;
    if (item >= NN * 3) return;
    const int i = item / 3;
    const int q = item - i * 3;                    // 8-col group within chunk
    const unsigned short* base = hp_c + (size_t)c * NN * CW + q * 8;

    ushort8 sv = *(const ushort8*)(base + (size_t)i * CW);  // self-loop term
    float a0 = bu2f(sv[0]), a1 = bu2f(sv[1]), a2 = bu2f(sv[2]), a3 = bu2f(sv[3]);
    float a4 = bu2f(sv[4]), a5 = bu2f(sv[5]), a6 = bu2f(sv[6]), a7 = bu2f(sv[7]);

    int idx = off[i];
    const int end = off[i + 1];
    const float dv = rsqrtf((float)(end - idx) + 1.f);
    for (; idx + 1 < end; idx += 2) {
        int s0 = csr[idx], s1 = csr[idx + 1];
        ushort8 v0 = *(const ushort8*)(base + (size_t)s0 * CW);
        ushort8 v1 = *(const ushort8*)(base + (size_t)s1 * CW);
        a0 += bu2f(v0[0]) + bu2f(v1[0]);
        a1 += bu2f(v0[1]) + bu2f(v1[1]);
        a2 += bu2f(v0[2]) + bu2f(v1[2]);
        a3 += bu2f(v0[3]) + bu2f(v1[3]);
        a4 += bu2f(v0[4]) + bu2f(v1[4]);
        a5 += bu2f(v0[5]) + bu2f(v1[5]);
        a6 += bu2f(v0[6]) + bu2f(v1[6]);
        a7 += bu2f(v0[7]) + bu2f(v1[7]);
    }
    if (idx < end) {
        ushort8 v0 = *(const ushort8*)(base + (size_t)csr[idx] * CW);
        a0 += bu2f(v0[0]); a1 += bu2f(v0[1]); a2 += bu2f(v0[2]); a3 += bu2f(v0[3]);
        a4 += bu2f(v0[4]); a5 += bu2f(v0[5]); a6 += bu2f(v0[6]); a7 += bu2f(v0[7]);
    }
    const int j = c * CW + q * 8;
    ushort8 o;
    o[0] = f2bu(fmaxf(fmaf(dv, a0, bg[j + 0]), 0.f));
    o[1] = f2bu(fmaxf(fmaf(dv, a1, bg[j + 1]), 0.f));
    o[2] = f2bu(fmaxf(fmaf(dv, a2, bg[j + 2]), 0.f));
    o[3] = f2bu(fmaxf(fmaf(dv, a3, bg[j + 3]), 0.f));
    o[4] = f2bu(fmaxf(fmaf(dv, a4, bg[j + 4]), 0.f));
    o[5] = f2bu(fmaxf(fmaf(dv, a5, bg[j + 5]), 0.f));
    o[6] = f2bu(fmaxf(fmaf(dv, a6, bg[j + 6]), 0.f));
    o[7] = f2bu(fmaxf(fmaf(dv, a7, bg[j + 7]), 0.f));
    *(ushort8*)(zb + (size_t)i * ZK + j) = o;
}

// ---- kernel 8: MFMA layer-1 + fused layer-2 dot epilogue ----
__global__ __launch_bounds__(256) void k_mlp2(const unsigned short* __restrict__ zb,
                                              const unsigned short* __restrict__ Wt1,
                                              const float* __restrict__ b1,
                                              const float* __restrict__ W2,
                                              const float* __restrict__ b2,
                                              const float* __restrict__ x,
                                              float* __restrict__ out) {
    const int wave = threadIdx.x >> 6;
    const int lane = threadIdx.x & 63;
    const int quad = lane >> 4;
    const int l16 = lane & 15;
    const int Mbase = blockIdx.x * 64 + wave * 16;

    const unsigned short* arow = zb + (size_t)(Mbase + l16) * ZK + quad * 8;
    const unsigned short* brow = Wt1 + (size_t)l16 * ZK + quad * 8;

    f32x4 acc[6] = {};
#pragma unroll
    for (int ks = 0; ks < 4; ++ks) {
        short8 a = *(const short8*)(arow + ks * 32);
#pragma unroll
        for (int nt = 0; nt < 6; ++nt) {
            short8 bfrag = *(const short8*)(brow + (size_t)nt * 16 * ZK + ks * 32);
            acc[nt] = __builtin_amdgcn_mfma_f32_16x16x32_bf16(a, bfrag, acc[nt], 0, 0, 0);
        }
    }
    float bb[6], wa[6];
#pragma unroll
    for (int nt = 0; nt < 6; ++nt) {
        int c = nt * 16 + l16;
        bb[nt] = b1[c];
        wa[nt] = W2[c];
    }
    float wx[8];
#pragma unroll
    for (int m = 0; m < 8; ++m) wx[m] = W2[HH + l16 * 8 + m];
    const float bias2 = b2[0];

#pragma unroll
    for (int reg = 0; reg < 4; ++reg) {
        const int r = Mbase + quad * 4 + reg;
        float p = 0.f;
#pragma unroll
        for (int nt = 0; nt < 6; ++nt)
            p = fmaf(fmaxf(acc[nt][reg] + bb[nt], 0.f), wa[nt], p);
        if (r < NN) {
            const float4 xa = *(const float4*)(x + (size_t)r * NF + l16 * 8);
            const float4 xc = *(const float4*)(x + (size_t)r * NF + l16 * 8 + 4);
            p = fmaf(xa.x, wx[0], p); p = fmaf(xa.y, wx[1], p);
            p = fmaf(xa.z, wx[2], p); p = fmaf(xa.w, wx[3], p);
            p = fmaf(xc.x, wx[4], p); p = fmaf(xc.y, wx[5], p);
            p = fmaf(xc.z, wx[6], p); p = fmaf(xc.w, wx[7], p);
        }
#pragma unroll
        for (int m = 1; m < 16; m <<= 1) p += __shfl_xor(p, m, 64);
        if (l16 == 0 && r < NN) out[r] = fmaxf(p + bias2, 0.f);
    }
}

extern "C" void kernel_launch(void* const* d_in, const int* in_sizes, int n_in,
                              void* d_out, int out_size, void* d_ws, size_t ws_size,
                              hipStream_t stream) {
    const float* x   = (const float*)d_in[0];
    const int*   ei  = (const int*)d_in[1];
    const float* tmp = (const float*)d_in[2];
    const float* Wg  = (const float*)d_in[3];
    const float* bg  = (const float*)d_in[4];
    const float* W1  = (const float*)d_in[5];
    const float* b1  = (const float*)d_in[6];
    const float* W2  = (const float*)d_in[7];
    const float* b2  = (const float*)d_in[8];
    float* out = (float*)d_out;

    char* base = (char*)d_ws;
    int* off  = (int*)base;                // NN+1 ints
    int* bcur = off + 65536;               // 256 ints
    int* gbase = bcur + 256;               // 256 ints
    int* csr  = gbase + 256;               // NE ints; all < 4 MiB
    unsigned short* xb = (unsigned short*)(base + ((size_t)4 << 20) + 262144);  // NPAD*NF bf16
    unsigned short* Wt = xb + (size_t)NPAD * NF;                 // NF*HH bf16
    unsigned short* hp_c = Wt + NF * HH;                         // NN*HH bf16 (chunked)
    unsigned short* Wt1 = hp_c + (size_t)NN * HH;                // HH*ZK bf16
    unsigned short* zb = Wt1 + HH * ZK;                          // NPAD*ZK bf16
    int* temp = (int*)zb;   // 196*5120 ints = 4.01 MB, aliases zb (consumed before zb written)

    k_init <<<1, 256, 0, stream>>>(bcur, off);
    k_fillA<<<(NE + EPB - 1) / EPB, 256, 0, stream>>>(ei, bcur, temp);
    k_gscan<<<1, 256, 0, stream>>>(bcur, gbase);
    k_fillB<<<NBK, 256, 0, stream>>>(temp, bcur, gbase, csr, off);
    k_prep <<<XBLK + WBLK + W1BLK + ZTBLK + ZPBLK, 256, 0, stream>>>(x, Wg, W1, tmp, xb, Wt, Wt1, zb);
    k_gemm <<<NPAD / 64, 256, 0, stream>>>(xb, Wt, off, hp_c);
    k_agg  <<<AGGB, 256, 0, stream>>>(hp_c, off, csr, bg, zb);
    k_mlp2 <<<NPAD / 64, 256, 0, stream>>>(zb, Wt1, b1, W2, b2, x, out);
}

// Round 11
// 189.186 us; speedup vs baseline: 8.1959x; 1.0321x over previous
//
#include <hip/hip_runtime.h>
#include <hip/hip_bf16.h>

#define NN 50000
#define NPAD 50048           // 64-row padded for MFMA grid
#define NE 800000
#define NF 128
#define HH 96
#define TF 10
#define Z1DIM (HH + TF)   // 106
#define ZK 128            // padded K for layer-1 MFMA
#define NCH 4             // column chunks for the gather
#define CW 24             // chunk width (cols): NCH*CW == HH
#define NBK 196           // dst buckets of 256 nodes
#define CAP 5120          // per-bucket temp capacity
#define EPB 8192          // edges per k_fillA block

typedef __attribute__((ext_vector_type(8))) short short8;
typedef __attribute__((ext_vector_type(8))) unsigned short ushort8;
typedef __attribute__((ext_vector_type(4))) float f32x4;

__device__ __forceinline__ float bu2f(unsigned short u) {
    union { unsigned int i; float f; } c;
    c.i = ((unsigned int)u) << 16;
    return c.f;
}
__device__ __forceinline__ unsigned short f2bu(float f) {
    union { __hip_bfloat16 h; unsigned short u; } c;
    c.h = __float2bfloat16(f);
    return c.u;
}

// ---- kernel 1: bcur[b] = b*CAP; off[NN] = NE ----
__global__ void k_init(int* __restrict__ bcur, int* __restrict__ off) {
    int t = threadIdx.x;
    if (t < NBK) bcur[t] = t * CAP;
    if (t == 255) off[NN] = NE;
}

// ---- kernel 2: bin edges into 196 dst-range buckets (counting-sort pass 1) ----
__global__ __launch_bounds__(256) void k_fillA(const int* __restrict__ ei,
                                               int* __restrict__ bcur,
                                               int* __restrict__ temp) {
    __shared__ int hist[NBK], base[NBK];
    const int t = threadIdx.x;
    for (int m = t; m < NBK; m += 256) hist[m] = 0;
    __syncthreads();
    const int e0 = blockIdx.x * EPB;
    const int ecap = min(e0 + EPB, NE);
    for (int e = e0 + t; e < ecap; e += 256) {
        int d = ei[NE + e];
        atomicAdd(&hist[d >> 8], 1);
    }
    __syncthreads();
    for (int m = t; m < NBK; m += 256) {
        int c = hist[m];
        base[m] = c ? atomicAdd(&bcur[m], c) : 0;
        hist[m] = 0;   // reuse as run cursor
    }
    __syncthreads();
    for (int e = e0 + t; e < ecap; e += 256) {
        int d = ei[NE + e], s = ei[e];
        int b = d >> 8;
        int r = atomicAdd(&hist[b], 1);
        temp[base[b] + r] = ((d & 255) << 16) | s;
    }
}

// ---- kernel 3: exclusive scan of bucket sizes -> gbase ----
__global__ __launch_bounds__(256) void k_gscan(const int* __restrict__ bcur,
                                               int* __restrict__ gbase) {
    __shared__ int p[256];
    const int t = threadIdx.x;
    int sz = (t < NBK) ? (bcur[t] - t * CAP) : 0;
    p[t] = sz;
    __syncthreads();
#pragma unroll
    for (int d = 1; d < 256; d <<= 1) {
        int u = (t >= d) ? p[t - d] : 0;
        __syncthreads();
        p[t] += u;
        __syncthreads();
    }
    if (t < NBK) gbase[t] = p[t] - sz;
}

// ---- kernel 4: per-bucket local sort -> csr(ushort), off ----
__global__ __launch_bounds__(256) void k_fillB(const int* __restrict__ temp,
                                               const int* __restrict__ bcur,
                                               const int* __restrict__ gbase,
                                               unsigned short* __restrict__ csr,
                                               int* __restrict__ off) {
    __shared__ int ls[256], lc[256];
    const int b = blockIdx.x, t = threadIdx.x;
    const int seg0 = b * CAP;
    const int m = bcur[b] - seg0;
    const int g0 = gbase[b];
    ls[t] = 0;
    __syncthreads();
    for (int k = t; k < m; k += 256) atomicAdd(&ls[temp[seg0 + k] >> 16], 1);
    __syncthreads();
    const int myc = ls[t];
    lc[t] = myc;
    __syncthreads();
#pragma unroll
    for (int d = 1; d < 256; d <<= 1) {
        int u = (t >= d) ? lc[t - d] : 0;
        __syncthreads();
        lc[t] += u;
        __syncthreads();
    }
    const int myoff = lc[t] - myc;    // exclusive within bucket
    __syncthreads();
    lc[t] = myoff;                    // cursor
    const int i = b * 256 + t;
    if (i < NN) off[i] = g0 + myoff;
    __syncthreads();
    for (int k = t; k < m; k += 256) {
        int v = temp[seg0 + k];
        int r = atomicAdd(&lc[v >> 16], 1);
        csr[g0 + r] = (unsigned short)(v & 0xFFFF);
    }
}

// ---- kernel 5: prep — Wt, Wt1, zb tail (cols 96..128 + pad rows) ----
#define WBLK (NF * HH / 4 / 256)       // 12
#define W1BLK (HH * ZK / 4 / 256)      // 12
#define ZTBLK (NPAD / 32)              // 1564 : NPAD*32 elems / 4 / 256
#define ZPBLK 5                        // (NPAD-NN)*HH elems / 4 / 256 -> 4.5
__global__ void k_prep(const float* __restrict__ W,
                       const float* __restrict__ W1, const float* __restrict__ tmp,
                       unsigned short* __restrict__ Wt,
                       unsigned short* __restrict__ Wt1, unsigned short* __restrict__ zb) {
    int b = blockIdx.x;
    if (b < WBLK) {
        int e = (b * 256 + threadIdx.x) * 4;
        int n = e >> 7, k = e & 127;
        ushort4 v;
        v.x = f2bu(W[(k + 0) * HH + n]);
        v.y = f2bu(W[(k + 1) * HH + n]);
        v.z = f2bu(W[(k + 2) * HH + n]);
        v.w = f2bu(W[(k + 3) * HH + n]);
        *(ushort4*)(Wt + e) = v;
    } else if (b < WBLK + W1BLK) {
        int e = ((b - WBLK) * 256 + threadIdx.x) * 4;
        int n = e >> 7, k = e & 127;     // n in [0,96), k in [0,128)
        ushort4 v;
        v.x = (k + 0 < Z1DIM) ? f2bu(W1[(k + 0) * HH + n]) : (unsigned short)0;
        v.y = (k + 1 < Z1DIM) ? f2bu(W1[(k + 1) * HH + n]) : (unsigned short)0;
        v.z = (k + 2 < Z1DIM) ? f2bu(W1[(k + 2) * HH + n]) : (unsigned short)0;
        v.w = (k + 3 < Z1DIM) ? f2bu(W1[(k + 3) * HH + n]) : (unsigned short)0;
        *(ushort4*)(Wt1 + e) = v;
    } else if (b < WBLK + W1BLK + ZTBLK) {
        // zb cols [96,128): temporal (cc<10) else 0
        int t4 = ((b - WBLK - W1BLK) * 256 + threadIdx.x) * 4;
        int i = t4 >> 5, cc = t4 & 31;
        ushort4 v; v.x = v.y = v.z = v.w = 0;
        if (i < NN) {
            if (cc + 0 < TF) v.x = f2bu(tmp[(size_t)i * TF + cc + 0]);
            if (cc + 1 < TF) v.y = f2bu(tmp[(size_t)i * TF + cc + 1]);
            if (cc + 2 < TF) v.z = f2bu(tmp[(size_t)i * TF + cc + 2]);
            if (cc + 3 < TF) v.w = f2bu(tmp[(size_t)i * TF + cc + 3]);
        }
        *(ushort4*)(zb + (size_t)i * ZK + HH + cc) = v;
    } else {
        // zb pad rows [NN,NPAD), cols [0,96): zero
        int t4 = ((b - WBLK - W1BLK - ZTBLK) * 256 + threadIdx.x) * 4;
        if (t4 < (NPAD - NN) * HH) {
            int i = NN + t4 / HH, j = t4 % HH;
            ushort4 z; z.x = z.y = z.z = z.w = 0;
            *(ushort4*)(zb + (size_t)i * ZK + j) = z;
        }
    }
}

// ---- kernel 6: MFMA GEMM, fp32 x loaded directly, in-register bf16 convert ----
__global__ __launch_bounds__(256) void k_gemm(const float* __restrict__ x,
                                              const unsigned short* __restrict__ Wt,
                                              const int* __restrict__ off,
                                              unsigned short* __restrict__ hp_c) {
    const int wave = threadIdx.x >> 6;
    const int lane = threadIdx.x & 63;
    const int quad = lane >> 4;
    const int l16 = lane & 15;
    const int Mbase = blockIdx.x * 64 + wave * 16;
    const int row = Mbase + l16;
    const bool valid = row < NN;

    const float* xr = x + (size_t)row * NF + quad * 8;
    const unsigned short* brow = Wt + (size_t)l16 * NF + quad * 8;

    f32x4 acc[6] = {};
#pragma unroll
    for (int ks = 0; ks < 4; ++ks) {
        short8 a = {};
        if (valid) {
            float4 f0 = *(const float4*)(xr + ks * 32);
            float4 f1 = *(const float4*)(xr + ks * 32 + 4);
            a[0] = (short)f2bu(f0.x); a[1] = (short)f2bu(f0.y);
            a[2] = (short)f2bu(f0.z); a[3] = (short)f2bu(f0.w);
            a[4] = (short)f2bu(f1.x); a[5] = (short)f2bu(f1.y);
            a[6] = (short)f2bu(f1.z); a[7] = (short)f2bu(f1.w);
        }
#pragma unroll
        for (int nt = 0; nt < 6; ++nt) {
            short8 bfrag = *(const short8*)(brow + (size_t)nt * 16 * NF + ks * 32);
            acc[nt] = __builtin_amdgcn_mfma_f32_16x16x32_bf16(a, bfrag, acc[nt], 0, 0, 0);
        }
    }
    const int r0 = Mbase + quad * 4;
    float dv[4];
#pragma unroll
    for (int k = 0; k < 4; ++k) {
        int r = r0 + k;
        dv[k] = (r < NN) ? rsqrtf((float)(off[r + 1] - off[r]) + 1.f) : 0.f;
    }
#pragma unroll
    for (int nt = 0; nt < 6; ++nt) {
        int n = nt * 16 + l16;
        int c = n / CW, jj = n - c * CW;
        unsigned short* dst = hp_c + (size_t)c * NN * CW + jj;
#pragma unroll
        for (int k = 0; k < 4; ++k)
            if (r0 + k < NN) dst[(size_t)(r0 + k) * CW] = f2bu(acc[nt][k] * dv[k]);
    }
}

// ---- kernel 7: chunked gather-aggregate -> zb[i][0..96), XCD-affine ----
// block decode: slot=b&7 -> chunk=slot>>1, half=slot&1 (pins each 2.4MB slice to 2 XCDs)
#define RPC 586                 // 256-thread rows per chunk: NN*3/256 rounded up
#define AGGB (4 * RPC)          // 2344 blocks total
__global__ __launch_bounds__(256) void k_agg(const unsigned short* __restrict__ hp_c,
                                             const int* __restrict__ off,
                                             const unsigned short* __restrict__ csr,
                                             const float* __restrict__ bg,
                                             unsigned short* __restrict__ zb) {
    const int b = blockIdx.x;
    const int slot = b & 7;
    const int c = slot >> 1;
    const int r = (b >> 3) * 2 + (slot & 1);       // 0..585
    const int item = r * 256 + threadIdx.x;
    if (item >= NN * 3) return;
    const int i = item / 3;
    const int q = item - i * 3;                    // 8-col group within chunk
    const unsigned short* base = hp_c + (size_t)c * NN * CW + q * 8;

    ushort8 sv = *(const ushort8*)(base + (size_t)i * CW);  // self-loop term
    float a0 = bu2f(sv[0]), a1 = bu2f(sv[1]), a2 = bu2f(sv[2]), a3 = bu2f(sv[3]);
    float a4 = bu2f(sv[4]), a5 = bu2f(sv[5]), a6 = bu2f(sv[6]), a7 = bu2f(sv[7]);

    int idx = off[i];
    const int end = off[i + 1];
    const float dv = rsqrtf((float)(end - idx) + 1.f);
    for (; idx + 1 < end; idx += 2) {
        int s0 = csr[idx], s1 = csr[idx + 1];
        ushort8 v0 = *(const ushort8*)(base + (size_t)s0 * CW);
        ushort8 v1 = *(const ushort8*)(base + (size_t)s1 * CW);
        a0 += bu2f(v0[0]) + bu2f(v1[0]);
        a1 += bu2f(v0[1]) + bu2f(v1[1]);
        a2 += bu2f(v0[2]) + bu2f(v1[2]);
        a3 += bu2f(v0[3]) + bu2f(v1[3]);
        a4 += bu2f(v0[4]) + bu2f(v1[4]);
        a5 += bu2f(v0[5]) + bu2f(v1[5]);
        a6 += bu2f(v0[6]) + bu2f(v1[6]);
        a7 += bu2f(v0[7]) + bu2f(v1[7]);
    }
    if (idx < end) {
        ushort8 v0 = *(const ushort8*)(base + (size_t)csr[idx] * CW);
        a0 += bu2f(v0[0]); a1 += bu2f(v0[1]); a2 += bu2f(v0[2]); a3 += bu2f(v0[3]);
        a4 += bu2f(v0[4]); a5 += bu2f(v0[5]); a6 += bu2f(v0[6]); a7 += bu2f(v0[7]);
    }
    const int j = c * CW + q * 8;
    ushort8 o;
    o[0] = f2bu(fmaxf(fmaf(dv, a0, bg[j + 0]), 0.f));
    o[1] = f2bu(fmaxf(fmaf(dv, a1, bg[j + 1]), 0.f));
    o[2] = f2bu(fmaxf(fmaf(dv, a2, bg[j + 2]), 0.f));
    o[3] = f2bu(fmaxf(fmaf(dv, a3, bg[j + 3]), 0.f));
    o[4] = f2bu(fmaxf(fmaf(dv, a4, bg[j + 4]), 0.f));
    o[5] = f2bu(fmaxf(fmaf(dv, a5, bg[j + 5]), 0.f));
    o[6] = f2bu(fmaxf(fmaf(dv, a6, bg[j + 6]), 0.f));
    o[7] = f2bu(fmaxf(fmaf(dv, a7, bg[j + 7]), 0.f));
    *(ushort8*)(zb + (size_t)i * ZK + j) = o;
}

// ---- kernel 8: MFMA layer-1 + fused layer-2 dot epilogue ----
__global__ __launch_bounds__(256) void k_mlp2(const unsigned short* __restrict__ zb,
                                              const unsigned short* __restrict__ Wt1,
                                              const float* __restrict__ b1,
                                              const float* __restrict__ W2,
                                              const float* __restrict__ b2,
                                              const float* __restrict__ x,
                                              float* __restrict__ out) {
    const int wave = threadIdx.x >> 6;
    const int lane = threadIdx.x & 63;
    const int quad = lane >> 4;
    const int l16 = lane & 15;
    const int Mbase = blockIdx.x * 64 + wave * 16;

    const unsigned short* arow = zb + (size_t)(Mbase + l16) * ZK + quad * 8;
    const unsigned short* brow = Wt1 + (size_t)l16 * ZK + quad * 8;

    f32x4 acc[6] = {};
#pragma unroll
    for (int ks = 0; ks < 4; ++ks) {
        short8 a = *(const short8*)(arow + ks * 32);
#pragma unroll
        for (int nt = 0; nt < 6; ++nt) {
            short8 bfrag = *(const short8*)(brow + (size_t)nt * 16 * ZK + ks * 32);
            acc[nt] = __builtin_amdgcn_mfma_f32_16x16x32_bf16(a, bfrag, acc[nt], 0, 0, 0);
        }
    }
    float bb[6], wa[6];
#pragma unroll
    for (int nt = 0; nt < 6; ++nt) {
        int c = nt * 16 + l16;
        bb[nt] = b1[c];
        wa[nt] = W2[c];
    }
    float wx[8];
#pragma unroll
    for (int m = 0; m < 8; ++m) wx[m] = W2[HH + l16 * 8 + m];
    const float bias2 = b2[0];

#pragma unroll
    for (int reg = 0; reg < 4; ++reg) {
        const int r = Mbase + quad * 4 + reg;
        float p = 0.f;
#pragma unroll
        for (int nt = 0; nt < 6; ++nt)
            p = fmaf(fmaxf(acc[nt][reg] + bb[nt], 0.f), wa[nt], p);
        if (r < NN) {
            const float4 xa = *(const float4*)(x + (size_t)r * NF + l16 * 8);
            const float4 xc = *(const float4*)(x + (size_t)r * NF + l16 * 8 + 4);
            p = fmaf(xa.x, wx[0], p); p = fmaf(xa.y, wx[1], p);
            p = fmaf(xa.z, wx[2], p); p = fmaf(xa.w, wx[3], p);
            p = fmaf(xc.x, wx[4], p); p = fmaf(xc.y, wx[5], p);
            p = fmaf(xc.z, wx[6], p); p = fmaf(xc.w, wx[7], p);
        }
#pragma unroll
        for (int m = 1; m < 16; m <<= 1) p += __shfl_xor(p, m, 64);
        if (l16 == 0 && r < NN) out[r] = fmaxf(p + bias2, 0.f);
    }
}

extern "C" void kernel_launch(void* const* d_in, const int* in_sizes, int n_in,
                              void* d_out, int out_size, void* d_ws, size_t ws_size,
                              hipStream_t stream) {
    const float* x   = (const float*)d_in[0];
    const int*   ei  = (const int*)d_in[1];
    const float* tmp = (const float*)d_in[2];
    const float* Wg  = (const float*)d_in[3];
    const float* bg  = (const float*)d_in[4];
    const float* W1  = (const float*)d_in[5];
    const float* b1  = (const float*)d_in[6];
    const float* W2  = (const float*)d_in[7];
    const float* b2  = (const float*)d_in[8];
    float* out = (float*)d_out;

    char* base = (char*)d_ws;
    int* off  = (int*)base;                         // NN+1 ints
    int* bcur = off + 65536;                        // 256 ints
    int* gbase = bcur + 256;                        // 256 ints
    unsigned short* csr = (unsigned short*)(gbase + 256);  // NE ushort = 1.6 MB; all < 4 MiB
    unsigned short* Wt  = (unsigned short*)(base + ((size_t)4 << 20));  // NF*HH bf16
    unsigned short* Wt1 = Wt + NF * HH;             // HH*ZK bf16
    unsigned short* hp_c = Wt1 + HH * ZK;           // NN*HH bf16 (chunked) = 9.6 MB
    unsigned short* zb = hp_c + (size_t)NN * HH;    // NPAD*ZK bf16 = 12.8 MB
    int* temp = (int*)zb;   // 196*5120 ints = 4.01 MB, aliases zb (consumed before zb written)

    k_init <<<1, 256, 0, stream>>>(bcur, off);
    k_fillA<<<(NE + EPB - 1) / EPB, 256, 0, stream>>>(ei, bcur, temp);
    k_gscan<<<1, 256, 0, stream>>>(bcur, gbase);
    k_fillB<<<NBK, 256, 0, stream>>>(temp, bcur, gbase, csr, off);
    k_prep <<<WBLK + W1BLK + ZTBLK + ZPBLK, 256, 0, stream>>>(Wg, W1, tmp, Wt, Wt1, zb);
    k_gemm <<<NPAD / 64, 256, 0, stream>>>(x, Wt, off, hp_c);
    k_agg  <<<AGGB, 256, 0, stream>>>(hp_c, off, csr, bg, zb);
    k_mlp2 <<<NPAD / 64, 256, 0, stream>>>(zb, Wt1, b1, W2, b2, x, out);
}

// Round 12
// 185.926 us; speedup vs baseline: 8.3396x; 1.0175x over previous
//
#include <hip/hip_runtime.h>
#include <hip/hip_bf16.h>

#define NN 50000
#define NPAD 50048           // 64-row padded for MFMA grid
#define NE 800000
#define NF 128
#define HH 96
#define TF 10
#define Z1DIM (HH + TF)   // 106
#define ZK 128            // padded K for layer-1 MFMA
#define NCH 4             // column chunks for the gather
#define CW 24             // chunk width (cols): NCH*CW == HH
#define NBK 196           // dst buckets of 256 nodes
#define CAP 5120          // per-bucket temp capacity
#define EPB 8192          // edges per k_fillA block

typedef __attribute__((ext_vector_type(8))) short short8;
typedef __attribute__((ext_vector_type(8))) unsigned short ushort8;
typedef __attribute__((ext_vector_type(4))) float f32x4;

__device__ __forceinline__ float bu2f(unsigned short u) {
    union { unsigned int i; float f; } c;
    c.i = ((unsigned int)u) << 16;
    return c.f;
}
__device__ __forceinline__ unsigned short f2bu(float f) {
    union { __hip_bfloat16 h; unsigned short u; } c;
    c.h = __float2bfloat16(f);
    return c.u;
}

// ---- kernel 1: bcur[b] = b*CAP; off[NN] = NE ----
__global__ void k_init(int* __restrict__ bcur, int* __restrict__ off) {
    int t = threadIdx.x;
    if (t < NBK) bcur[t] = t * CAP;
    if (t == 255) off[NN] = NE;
}

// ---- kernel 2: bin edges into 196 dst-range buckets (counting-sort pass 1) ----
__global__ __launch_bounds__(256) void k_fillA(const int* __restrict__ ei,
                                               int* __restrict__ bcur,
                                               int* __restrict__ temp) {
    __shared__ int hist[NBK], base[NBK];
    const int t = threadIdx.x;
    for (int m = t; m < NBK; m += 256) hist[m] = 0;
    __syncthreads();
    const int e0 = blockIdx.x * EPB;
    const int ecap = min(e0 + EPB, NE);
    for (int e = e0 + t; e < ecap; e += 256) {
        int d = ei[NE + e];
        atomicAdd(&hist[d >> 8], 1);
    }
    __syncthreads();
    for (int m = t; m < NBK; m += 256) {
        int c = hist[m];
        base[m] = c ? atomicAdd(&bcur[m], c) : 0;
        hist[m] = 0;   // reuse as run cursor
    }
    __syncthreads();
    for (int e = e0 + t; e < ecap; e += 256) {
        int d = ei[NE + e], s = ei[e];
        int b = d >> 8;
        int r = atomicAdd(&hist[b], 1);
        temp[base[b] + r] = ((d & 255) << 16) | s;
    }
}

// ---- kernel 3: exclusive scan of bucket sizes -> gbase ----
__global__ __launch_bounds__(256) void k_gscan(const int* __restrict__ bcur,
                                               int* __restrict__ gbase) {
    __shared__ int p[256];
    const int t = threadIdx.x;
    int sz = (t < NBK) ? (bcur[t] - t * CAP) : 0;
    p[t] = sz;
    __syncthreads();
#pragma unroll
    for (int d = 1; d < 256; d <<= 1) {
        int u = (t >= d) ? p[t - d] : 0;
        __syncthreads();
        p[t] += u;
        __syncthreads();
    }
    if (t < NBK) gbase[t] = p[t] - sz;
}

// ---- kernel 4: per-bucket local sort -> csr(ushort), off ----
__global__ __launch_bounds__(256) void k_fillB(const int* __restrict__ temp,
                                               const int* __restrict__ bcur,
                                               const int* __restrict__ gbase,
                                               unsigned short* __restrict__ csr,
                                               int* __restrict__ off) {
    __shared__ int ls[256], lc[256];
    const int b = blockIdx.x, t = threadIdx.x;
    const int seg0 = b * CAP;
    const int m = bcur[b] - seg0;
    const int g0 = gbase[b];
    ls[t] = 0;
    __syncthreads();
    for (int k = t; k < m; k += 256) atomicAdd(&ls[temp[seg0 + k] >> 16], 1);
    __syncthreads();
    const int myc = ls[t];
    lc[t] = myc;
    __syncthreads();
#pragma unroll
    for (int d = 1; d < 256; d <<= 1) {
        int u = (t >= d) ? lc[t - d] : 0;
        __syncthreads();
        lc[t] += u;
        __syncthreads();
    }
    const int myoff = lc[t] - myc;    // exclusive within bucket
    __syncthreads();
    lc[t] = myoff;                    // cursor
    const int i = b * 256 + t;
    if (i < NN) off[i] = g0 + myoff;
    __syncthreads();
    for (int k = t; k < m; k += 256) {
        int v = temp[seg0 + k];
        int r = atomicAdd(&lc[v >> 16], 1);
        csr[g0 + r] = (unsigned short)(v & 0xFFFF);
    }
}

// ---- kernel 5: prep — Wt, Wt1, zb tail (cols 96..128 + pad rows) ----
#define WBLK (NF * HH / 4 / 256)       // 12
#define W1BLK (HH * ZK / 4 / 256)      // 12
#define ZTBLK (NPAD / 32)              // 1564 : NPAD*32 elems / 4 / 256
#define ZPBLK 5                        // (NPAD-NN)*HH elems / 4 / 256 -> 4.5
__global__ void k_prep(const float* __restrict__ W,
                       const float* __restrict__ W1, const float* __restrict__ tmp,
                       unsigned short* __restrict__ Wt,
                       unsigned short* __restrict__ Wt1, unsigned short* __restrict__ zb) {
    int b = blockIdx.x;
    if (b < WBLK) {
        int e = (b * 256 + threadIdx.x) * 4;
        int n = e >> 7, k = e & 127;
        ushort4 v;
        v.x = f2bu(W[(k + 0) * HH + n]);
        v.y = f2bu(W[(k + 1) * HH + n]);
        v.z = f2bu(W[(k + 2) * HH + n]);
        v.w = f2bu(W[(k + 3) * HH + n]);
        *(ushort4*)(Wt + e) = v;
    } else if (b < WBLK + W1BLK) {
        int e = ((b - WBLK) * 256 + threadIdx.x) * 4;
        int n = e >> 7, k = e & 127;     // n in [0,96), k in [0,128)
        ushort4 v;
        v.x = (k + 0 < Z1DIM) ? f2bu(W1[(k + 0) * HH + n]) : (unsigned short)0;
        v.y = (k + 1 < Z1DIM) ? f2bu(W1[(k + 1) * HH + n]) : (unsigned short)0;
        v.z = (k + 2 < Z1DIM) ? f2bu(W1[(k + 2) * HH + n]) : (unsigned short)0;
        v.w = (k + 3 < Z1DIM) ? f2bu(W1[(k + 3) * HH + n]) : (unsigned short)0;
        *(ushort4*)(Wt1 + e) = v;
    } else if (b < WBLK + W1BLK + ZTBLK) {
        // zb cols [96,128): temporal (cc<10) else 0
        int t4 = ((b - WBLK - W1BLK) * 256 + threadIdx.x) * 4;
        int i = t4 >> 5, cc = t4 & 31;
        ushort4 v; v.x = v.y = v.z = v.w = 0;
        if (i < NN) {
            if (cc + 0 < TF) v.x = f2bu(tmp[(size_t)i * TF + cc + 0]);
            if (cc + 1 < TF) v.y = f2bu(tmp[(size_t)i * TF + cc + 1]);
            if (cc + 2 < TF) v.z = f2bu(tmp[(size_t)i * TF + cc + 2]);
            if (cc + 3 < TF) v.w = f2bu(tmp[(size_t)i * TF + cc + 3]);
        }
        *(ushort4*)(zb + (size_t)i * ZK + HH + cc) = v;
    } else {
        // zb pad rows [NN,NPAD), cols [0,96): zero
        int t4 = ((b - WBLK - W1BLK - ZTBLK) * 256 + threadIdx.x) * 4;
        if (t4 < (NPAD - NN) * HH) {
            int i = NN + t4 / HH, j = t4 % HH;
            ushort4 z; z.x = z.y = z.z = z.w = 0;
            *(ushort4*)(zb + (size_t)i * ZK + j) = z;
        }
    }
}

// ---- kernel 6: MFMA GEMM + fused x·W2[96:224] row-dot (xw2) ----
__global__ __launch_bounds__(256) void k_gemm(const float* __restrict__ x,
                                              const unsigned short* __restrict__ Wt,
                                              const int* __restrict__ off,
                                              const float* __restrict__ W2,
                                              unsigned short* __restrict__ hp_c,
                                              float* __restrict__ xw2) {
    const int wave = threadIdx.x >> 6;
    const int lane = threadIdx.x & 63;
    const int quad = lane >> 4;
    const int l16 = lane & 15;
    const int Mbase = blockIdx.x * 64 + wave * 16;
    const int row = Mbase + l16;
    const bool valid = row < NN;

    const float* xr = x + (size_t)row * NF + quad * 8;
    const unsigned short* brow = Wt + (size_t)l16 * NF + quad * 8;

    f32x4 acc[6] = {};
    float xs = 0.f;   // partial of sum_k x[row][k] * W2[96+k] over this lane's 32 cols
#pragma unroll
    for (int ks = 0; ks < 4; ++ks) {
        short8 a = {};
        if (valid) {
            float4 f0 = *(const float4*)(xr + ks * 32);
            float4 f1 = *(const float4*)(xr + ks * 32 + 4);
            const float4 w0 = *(const float4*)(W2 + HH + quad * 8 + ks * 32);
            const float4 w1 = *(const float4*)(W2 + HH + quad * 8 + ks * 32 + 4);
            xs = fmaf(f0.x, w0.x, xs); xs = fmaf(f0.y, w0.y, xs);
            xs = fmaf(f0.z, w0.z, xs); xs = fmaf(f0.w, w0.w, xs);
            xs = fmaf(f1.x, w1.x, xs); xs = fmaf(f1.y, w1.y, xs);
            xs = fmaf(f1.z, w1.z, xs); xs = fmaf(f1.w, w1.w, xs);
            a[0] = (short)f2bu(f0.x); a[1] = (short)f2bu(f0.y);
            a[2] = (short)f2bu(f0.z); a[3] = (short)f2bu(f0.w);
            a[4] = (short)f2bu(f1.x); a[5] = (short)f2bu(f1.y);
            a[6] = (short)f2bu(f1.z); a[7] = (short)f2bu(f1.w);
        }
#pragma unroll
        for (int nt = 0; nt < 6; ++nt) {
            short8 bfrag = *(const short8*)(brow + (size_t)nt * 16 * NF + ks * 32);
            acc[nt] = __builtin_amdgcn_mfma_f32_16x16x32_bf16(a, bfrag, acc[nt], 0, 0, 0);
        }
    }
    // cross-quad reduce of xs (lanes quad*16+l16 share a row)
    xs += __shfl_xor(xs, 16, 64);
    xs += __shfl_xor(xs, 32, 64);
    if (quad == 0 && valid) xw2[row] = xs;

    const int r0 = Mbase + quad * 4;
    float dv[4];
#pragma unroll
    for (int k = 0; k < 4; ++k) {
        int r = r0 + k;
        dv[k] = (r < NN) ? rsqrtf((float)(off[r + 1] - off[r]) + 1.f) : 0.f;
    }
#pragma unroll
    for (int nt = 0; nt < 6; ++nt) {
        int n = nt * 16 + l16;
        int c = n / CW, jj = n - c * CW;
        unsigned short* dst = hp_c + (size_t)c * NN * CW + jj;
#pragma unroll
        for (int k = 0; k < 4; ++k)
            if (r0 + k < NN) dst[(size_t)(r0 + k) * CW] = f2bu(acc[nt][k] * dv[k]);
    }
}

// ---- kernel 7: chunked gather-aggregate -> zb[i][0..96), XCD-affine, unroll-4 ----
#define RPC 586                 // 256-thread rows per chunk: NN*3/256 rounded up
#define AGGB (4 * RPC)          // 2344 blocks total
__global__ __launch_bounds__(256) void k_agg(const unsigned short* __restrict__ hp_c,
                                             const int* __restrict__ off,
                                             const unsigned short* __restrict__ csr,
                                             const float* __restrict__ bg,
                                             unsigned short* __restrict__ zb) {
    const int b = blockIdx.x;
    const int slot = b & 7;
    const int c = slot >> 1;
    const int r = (b >> 3) * 2 + (slot & 1);       // 0..585
    const int item = r * 256 + threadIdx.x;
    if (item >= NN * 3) return;
    const int i = item / 3;
    const int q = item - i * 3;                    // 8-col group within chunk
    const unsigned short* base = hp_c + (size_t)c * NN * CW + q * 8;

    ushort8 sv = *(const ushort8*)(base + (size_t)i * CW);  // self-loop term
    float a0 = bu2f(sv[0]), a1 = bu2f(sv[1]), a2 = bu2f(sv[2]), a3 = bu2f(sv[3]);
    float a4 = bu2f(sv[4]), a5 = bu2f(sv[5]), a6 = bu2f(sv[6]), a7 = bu2f(sv[7]);

    int idx = off[i];
    const int end = off[i + 1];
    const float dv = rsqrtf((float)(end - idx) + 1.f);
    for (; idx + 3 < end; idx += 4) {
        int s0 = csr[idx], s1 = csr[idx + 1], s2 = csr[idx + 2], s3 = csr[idx + 3];
        ushort8 v0 = *(const ushort8*)(base + (size_t)s0 * CW);
        ushort8 v1 = *(const ushort8*)(base + (size_t)s1 * CW);
        ushort8 v2 = *(const ushort8*)(base + (size_t)s2 * CW);
        ushort8 v3 = *(const ushort8*)(base + (size_t)s3 * CW);
        a0 += (bu2f(v0[0]) + bu2f(v1[0])) + (bu2f(v2[0]) + bu2f(v3[0]));
        a1 += (bu2f(v0[1]) + bu2f(v1[1])) + (bu2f(v2[1]) + bu2f(v3[1]));
        a2 += (bu2f(v0[2]) + bu2f(v1[2])) + (bu2f(v2[2]) + bu2f(v3[2]));
        a3 += (bu2f(v0[3]) + bu2f(v1[3])) + (bu2f(v2[3]) + bu2f(v3[3]));
        a4 += (bu2f(v0[4]) + bu2f(v1[4])) + (bu2f(v2[4]) + bu2f(v3[4]));
        a5 += (bu2f(v0[5]) + bu2f(v1[5])) + (bu2f(v2[5]) + bu2f(v3[5]));
        a6 += (bu2f(v0[6]) + bu2f(v1[6])) + (bu2f(v2[6]) + bu2f(v3[6]));
        a7 += (bu2f(v0[7]) + bu2f(v1[7])) + (bu2f(v2[7]) + bu2f(v3[7]));
    }
    for (; idx < end; ++idx) {
        ushort8 v0 = *(const ushort8*)(base + (size_t)csr[idx] * CW);
        a0 += bu2f(v0[0]); a1 += bu2f(v0[1]); a2 += bu2f(v0[2]); a3 += bu2f(v0[3]);
        a4 += bu2f(v0[4]); a5 += bu2f(v0[5]); a6 += bu2f(v0[6]); a7 += bu2f(v0[7]);
    }
    const int j = c * CW + q * 8;
    ushort8 o;
    o[0] = f2bu(fmaxf(fmaf(dv, a0, bg[j + 0]), 0.f));
    o[1] = f2bu(fmaxf(fmaf(dv, a1, bg[j + 1]), 0.f));
    o[2] = f2bu(fmaxf(fmaf(dv, a2, bg[j + 2]), 0.f));
    o[3] = f2bu(fmaxf(fmaf(dv, a3, bg[j + 3]), 0.f));
    o[4] = f2bu(fmaxf(fmaf(dv, a4, bg[j + 4]), 0.f));
    o[5] = f2bu(fmaxf(fmaf(dv, a5, bg[j + 5]), 0.f));
    o[6] = f2bu(fmaxf(fmaf(dv, a6, bg[j + 6]), 0.f));
    o[7] = f2bu(fmaxf(fmaf(dv, a7, bg[j + 7]), 0.f));
    *(ushort8*)(zb + (size_t)i * ZK + j) = o;
}

// ---- kernel 8: MFMA layer-1 + fused layer-2 epilogue (x·W2 via precomputed xw2) ----
__global__ __launch_bounds__(256) void k_mlp2(const unsigned short* __restrict__ zb,
                                              const unsigned short* __restrict__ Wt1,
                                              const float* __restrict__ b1,
                                              const float* __restrict__ W2,
                                              const float* __restrict__ b2,
                                              const float* __restrict__ xw2,
                                              float* __restrict__ out) {
    const int wave = threadIdx.x >> 6;
    const int lane = threadIdx.x & 63;
    const int quad = lane >> 4;
    const int l16 = lane & 15;
    const int Mbase = blockIdx.x * 64 + wave * 16;

    const unsigned short* arow = zb + (size_t)(Mbase + l16) * ZK + quad * 8;
    const unsigned short* brow = Wt1 + (size_t)l16 * ZK + quad * 8;

    f32x4 acc[6] = {};
#pragma unroll
    for (int ks = 0; ks < 4; ++ks) {
        short8 a = *(const short8*)(arow + ks * 32);
#pragma unroll
        for (int nt = 0; nt < 6; ++nt) {
            short8 bfrag = *(const short8*)(brow + (size_t)nt * 16 * ZK + ks * 32);
            acc[nt] = __builtin_amdgcn_mfma_f32_16x16x32_bf16(a, bfrag, acc[nt], 0, 0, 0);
        }
    }
    float bb[6], wa[6];
#pragma unroll
    for (int nt = 0; nt < 6; ++nt) {
        int c = nt * 16 + l16;
        bb[nt] = b1[c];
        wa[nt] = W2[c];
    }
    const float bias2 = b2[0];

#pragma unroll
    for (int reg = 0; reg < 4; ++reg) {
        const int r = Mbase + quad * 4 + reg;
        float p = 0.f;
#pragma unroll
        for (int nt = 0; nt < 6; ++nt)
            p = fmaf(fmaxf(acc[nt][reg] + bb[nt], 0.f), wa[nt], p);
#pragma unroll
        for (int m = 1; m < 16; m <<= 1) p += __shfl_xor(p, m, 64);
        if (l16 == 0 && r < NN) out[r] = fmaxf(p + xw2[r] + bias2, 0.f);
    }
}

extern "C" void kernel_launch(void* const* d_in, const int* in_sizes, int n_in,
                              void* d_out, int out_size, void* d_ws, size_t ws_size,
                              hipStream_t stream) {
    const float* x   = (const float*)d_in[0];
    const int*   ei  = (const int*)d_in[1];
    const float* tmp = (const float*)d_in[2];
    const float* Wg  = (const float*)d_in[3];
    const float* bg  = (const float*)d_in[4];
    const float* W1  = (const float*)d_in[5];
    const float* b1  = (const float*)d_in[6];
    const float* W2  = (const float*)d_in[7];
    const float* b2  = (const float*)d_in[8];
    float* out = (float*)d_out;

    char* base = (char*)d_ws;
    int* off  = (int*)base;                         // NN+1 ints
    int* bcur = off + 65536;                        // 256 ints
    int* gbase = bcur + 256;                        // 256 ints
    unsigned short* csr = (unsigned short*)(gbase + 256);  // NE ushort = 1.6 MB; all < 4 MiB
    unsigned short* Wt  = (unsigned short*)(base + ((size_t)4 << 20));  // NF*HH bf16
    unsigned short* Wt1 = Wt + NF * HH;             // HH*ZK bf16
    unsigned short* hp_c = Wt1 + HH * ZK;           // NN*HH bf16 (chunked) = 9.6 MB
    unsigned short* zb = hp_c + (size_t)NN * HH;    // NPAD*ZK bf16 = 12.8 MB
    float* xw2 = (float*)(zb + (size_t)NPAD * ZK);  // NPAD floats = 200 KB
    int* temp = (int*)zb;   // 196*5120 ints = 4.01 MB, aliases zb (consumed before zb written)

    k_init <<<1, 256, 0, stream>>>(bcur, off);
    k_fillA<<<(NE + EPB - 1) / EPB, 256, 0, stream>>>(ei, bcur, temp);
    k_gscan<<<1, 256, 0, stream>>>(bcur, gbase);
    k_fillB<<<NBK, 256, 0, stream>>>(temp, bcur, gbase, csr, off);
    k_prep <<<WBLK + W1BLK + ZTBLK + ZPBLK, 256, 0, stream>>>(Wg, W1, tmp, Wt, Wt1, zb);
    k_gemm <<<NPAD / 64, 256, 0, stream>>>(x, Wt, off, W2, hp_c, xw2);
    k_agg  <<<AGGB, 256, 0, stream>>>(hp_c, off, csr, bg, zb);
    k_mlp2 <<<NPAD / 64, 256, 0, stream>>>(zb, Wt1, b1, W2, b2, xw2, out);
}

// Round 13
// 182.341 us; speedup vs baseline: 8.5035x; 1.0197x over previous
//
#include <hip/hip_runtime.h>
#include <hip/hip_bf16.h>

#define NN 50000
#define NPAD 50048           // 64-row padded for MFMA grid
#define NE 800000
#define NF 128
#define HH 96
#define TF 10
#define Z1DIM (HH + TF)   // 106
#define ZK 128            // padded K for layer-1 MFMA
#define NCH 4             // column chunks for the gather
#define CW 24             // chunk width (cols): NCH*CW == HH
#define NBK 196           // dst buckets of 256 nodes
#define CAP 5120          // per-bucket temp capacity
#define EPB 8192          // edges per k_fillA block

typedef __attribute__((ext_vector_type(8))) short short8;
typedef __attribute__((ext_vector_type(8))) unsigned short ushort8;
typedef __attribute__((ext_vector_type(4))) float f32x4;

__device__ __forceinline__ float bu2f(unsigned short u) {
    union { unsigned int i; float f; } c;
    c.i = ((unsigned int)u) << 16;
    return c.f;
}
__device__ __forceinline__ unsigned short f2bu(float f) {
    union { __hip_bfloat16 h; unsigned short u; } c;
    c.h = __float2bfloat16(f);
    return c.u;
}

// ---- kernel 1: bcur[b] = b*CAP; off[NN] = NE ----
__global__ void k_init(int* __restrict__ bcur, int* __restrict__ off) {
    int t = threadIdx.x;
    if (t < NBK) bcur[t] = t * CAP;
    if (t == 255) off[NN] = NE;
}

// ---- kernel 2: bin edges into 196 dst-range buckets (counting-sort pass 1) ----
__global__ __launch_bounds__(256) void k_fillA(const int* __restrict__ ei,
                                               int* __restrict__ bcur,
                                               int* __restrict__ temp) {
    __shared__ int hist[NBK], base[NBK];
    const int t = threadIdx.x;
    for (int m = t; m < NBK; m += 256) hist[m] = 0;
    __syncthreads();
    const int e0 = blockIdx.x * EPB;
    const int ecap = min(e0 + EPB, NE);
    for (int e = e0 + t; e < ecap; e += 256) {
        int d = ei[NE + e];
        atomicAdd(&hist[d >> 8], 1);
    }
    __syncthreads();
    for (int m = t; m < NBK; m += 256) {
        int c = hist[m];
        base[m] = c ? atomicAdd(&bcur[m], c) : 0;
        hist[m] = 0;   // reuse as run cursor
    }
    __syncthreads();
    for (int e = e0 + t; e < ecap; e += 256) {
        int d = ei[NE + e], s = ei[e];
        int b = d >> 8;
        int r = atomicAdd(&hist[b], 1);
        temp[base[b] + r] = ((d & 255) << 16) | s;
    }
}

// ---- kernel 3: per-bucket local sort -> csr(ushort), off (gbase scan inlined) ----
__global__ __launch_bounds__(256) void k_fillB(const int* __restrict__ temp,
                                               const int* __restrict__ bcur,
                                               unsigned short* __restrict__ csr,
                                               int* __restrict__ off) {
    __shared__ int ls[256], lc[256];
    const int b = blockIdx.x, t = threadIdx.x;
    // inline exclusive scan of all bucket sizes -> this bucket's global base g0
    int szt = (t < NBK) ? (bcur[t] - t * CAP) : 0;
    ls[t] = szt;
    __syncthreads();
#pragma unroll
    for (int d = 1; d < 256; d <<= 1) {
        int u = (t >= d) ? ls[t - d] : 0;
        __syncthreads();
        ls[t] += u;
        __syncthreads();
    }
    const int g0 = (b > 0) ? ls[b - 1] : 0;
    __syncthreads();
    ls[t] = 0;
    __syncthreads();
    const int seg0 = b * CAP;
    const int m = bcur[b] - seg0;
    for (int k = t; k < m; k += 256) atomicAdd(&ls[temp[seg0 + k] >> 16], 1);
    __syncthreads();
    const int myc = ls[t];
    lc[t] = myc;
    __syncthreads();
#pragma unroll
    for (int d = 1; d < 256; d <<= 1) {
        int u = (t >= d) ? lc[t - d] : 0;
        __syncthreads();
        lc[t] += u;
        __syncthreads();
    }
    const int myoff = lc[t] - myc;    // exclusive within bucket
    __syncthreads();
    lc[t] = myoff;                    // cursor
    const int i = b * 256 + t;
    if (i < NN) off[i] = g0 + myoff;
    __syncthreads();
    for (int k = t; k < m; k += 256) {
        int v = temp[seg0 + k];
        int r = atomicAdd(&lc[v >> 16], 1);
        csr[g0 + r] = (unsigned short)(v & 0xFFFF);
    }
}

// ---- kernel 4: prep — Wt, Wt1, zb tail (cols 96..128 + pad rows) ----
#define WBLK (NF * HH / 4 / 256)       // 12
#define W1BLK (HH * ZK / 4 / 256)      // 12
#define ZTBLK (NPAD / 32)              // 1564 : NPAD*32 elems / 4 / 256
#define ZPBLK 5                        // (NPAD-NN)*HH elems / 4 / 256 -> 4.5
__global__ void k_prep(const float* __restrict__ W,
                       const float* __restrict__ W1, const float* __restrict__ tmp,
                       unsigned short* __restrict__ Wt,
                       unsigned short* __restrict__ Wt1, unsigned short* __restrict__ zb) {
    int b = blockIdx.x;
    if (b < WBLK) {
        int e = (b * 256 + threadIdx.x) * 4;
        int n = e >> 7, k = e & 127;
        ushort4 v;
        v.x = f2bu(W[(k + 0) * HH + n]);
        v.y = f2bu(W[(k + 1) * HH + n]);
        v.z = f2bu(W[(k + 2) * HH + n]);
        v.w = f2bu(W[(k + 3) * HH + n]);
        *(ushort4*)(Wt + e) = v;
    } else if (b < WBLK + W1BLK) {
        int e = ((b - WBLK) * 256 + threadIdx.x) * 4;
        int n = e >> 7, k = e & 127;     // n in [0,96), k in [0,128)
        ushort4 v;
        v.x = (k + 0 < Z1DIM) ? f2bu(W1[(k + 0) * HH + n]) : (unsigned short)0;
        v.y = (k + 1 < Z1DIM) ? f2bu(W1[(k + 1) * HH + n]) : (unsigned short)0;
        v.z = (k + 2 < Z1DIM) ? f2bu(W1[(k + 2) * HH + n]) : (unsigned short)0;
        v.w = (k + 3 < Z1DIM) ? f2bu(W1[(k + 3) * HH + n]) : (unsigned short)0;
        *(ushort4*)(Wt1 + e) = v;
    } else if (b < WBLK + W1BLK + ZTBLK) {
        // zb cols [96,128): temporal (cc<10) else 0
        int t4 = ((b - WBLK - W1BLK) * 256 + threadIdx.x) * 4;
        int i = t4 >> 5, cc = t4 & 31;
        ushort4 v; v.x = v.y = v.z = v.w = 0;
        if (i < NN) {
            if (cc + 0 < TF) v.x = f2bu(tmp[(size_t)i * TF + cc + 0]);
            if (cc + 1 < TF) v.y = f2bu(tmp[(size_t)i * TF + cc + 1]);
            if (cc + 2 < TF) v.z = f2bu(tmp[(size_t)i * TF + cc + 2]);
            if (cc + 3 < TF) v.w = f2bu(tmp[(size_t)i * TF + cc + 3]);
        }
        *(ushort4*)(zb + (size_t)i * ZK + HH + cc) = v;
    } else {
        // zb pad rows [NN,NPAD), cols [0,96): zero
        int t4 = ((b - WBLK - W1BLK - ZTBLK) * 256 + threadIdx.x) * 4;
        if (t4 < (NPAD - NN) * HH) {
            int i = NN + t4 / HH, j = t4 % HH;
            ushort4 z; z.x = z.y = z.z = z.w = 0;
            *(ushort4*)(zb + (size_t)i * ZK + j) = z;
        }
    }
}

// ---- kernel 5: MFMA GEMM + fused x·W2[96:224] row-dot (xw2) ----
__global__ __launch_bounds__(256) void k_gemm(const float* __restrict__ x,
                                              const unsigned short* __restrict__ Wt,
                                              const int* __restrict__ off,
                                              const float* __restrict__ W2,
                                              unsigned short* __restrict__ hp_c,
                                              float* __restrict__ xw2) {
    const int wave = threadIdx.x >> 6;
    const int lane = threadIdx.x & 63;
    const int quad = lane >> 4;
    const int l16 = lane & 15;
    const int Mbase = blockIdx.x * 64 + wave * 16;
    const int row = Mbase + l16;
    const bool valid = row < NN;

    const float* xr = x + (size_t)row * NF + quad * 8;
    const unsigned short* brow = Wt + (size_t)l16 * NF + quad * 8;

    f32x4 acc[6] = {};
    float xs = 0.f;   // partial of sum_k x[row][k] * W2[96+k] over this lane's 32 cols
#pragma unroll
    for (int ks = 0; ks < 4; ++ks) {
        short8 a = {};
        if (valid) {
            float4 f0 = *(const float4*)(xr + ks * 32);
            float4 f1 = *(const float4*)(xr + ks * 32 + 4);
            const float4 w0 = *(const float4*)(W2 + HH + quad * 8 + ks * 32);
            const float4 w1 = *(const float4*)(W2 + HH + quad * 8 + ks * 32 + 4);
            xs = fmaf(f0.x, w0.x, xs); xs = fmaf(f0.y, w0.y, xs);
            xs = fmaf(f0.z, w0.z, xs); xs = fmaf(f0.w, w0.w, xs);
            xs = fmaf(f1.x, w1.x, xs); xs = fmaf(f1.y, w1.y, xs);
            xs = fmaf(f1.z, w1.z, xs); xs = fmaf(f1.w, w1.w, xs);
            a[0] = (short)f2bu(f0.x); a[1] = (short)f2bu(f0.y);
            a[2] = (short)f2bu(f0.z); a[3] = (short)f2bu(f0.w);
            a[4] = (short)f2bu(f1.x); a[5] = (short)f2bu(f1.y);
            a[6] = (short)f2bu(f1.z); a[7] = (short)f2bu(f1.w);
        }
#pragma unroll
        for (int nt = 0; nt < 6; ++nt) {
            short8 bfrag = *(const short8*)(brow + (size_t)nt * 16 * NF + ks * 32);
            acc[nt] = __builtin_amdgcn_mfma_f32_16x16x32_bf16(a, bfrag, acc[nt], 0, 0, 0);
        }
    }
    // cross-quad reduce of xs (lanes quad*16+l16 share a row)
    xs += __shfl_xor(xs, 16, 64);
    xs += __shfl_xor(xs, 32, 64);
    if (quad == 0 && valid) xw2[row] = xs;

    const int r0 = Mbase + quad * 4;
    float dv[4];
#pragma unroll
    for (int k = 0; k < 4; ++k) {
        int r = r0 + k;
        dv[k] = (r < NN) ? rsqrtf((float)(off[r + 1] - off[r]) + 1.f) : 0.f;
    }
#pragma unroll
    for (int nt = 0; nt < 6; ++nt) {
        int n = nt * 16 + l16;
        int c = n / CW, jj = n - c * CW;
        unsigned short* dst = hp_c + (size_t)c * NN * CW + jj;
#pragma unroll
        for (int k = 0; k < 4; ++k)
            if (r0 + k < NN) dst[(size_t)(r0 + k) * CW] = f2bu(acc[nt][k] * dv[k]);
    }
}

// ---- kernel 6: chunked gather-aggregate -> zb[i][0..96), XCD-affine ----
// 2 threads per (node, 8-col group): adjacent lanes split the edge list by
// stride-2 parity, combine via shfl_xor(1). Halves the per-lane latency chain.
#define RPC2 1172               // 256-thread rows per chunk: NN*6/256 rounded up
#define AGGB (4 * RPC2)         // 4688 blocks total
__global__ __launch_bounds__(256) void k_agg(const unsigned short* __restrict__ hp_c,
                                             const int* __restrict__ off,
                                             const unsigned short* __restrict__ csr,
                                             const float* __restrict__ bg,
                                             unsigned short* __restrict__ zb) {
    const int b = blockIdx.x;
    const int slot = b & 7;
    const int c = slot >> 1;                       // chunk: pinned to XCD pair
    const int r = (b >> 3) * 2 + (slot & 1);       // 0..1171
    const int item = r * 256 + threadIdx.x;
    if (item >= NN * 6) return;
    const int i = item / 6;
    const int sub = item - i * 6;
    const int q = sub >> 1;                        // 8-col group within chunk
    const int h = sub & 1;                         // edge-parity half (== lane parity)
    const unsigned short* base = hp_c + (size_t)c * NN * CW + q * 8;

    float a0, a1, a2, a3, a4, a5, a6, a7;
    if (h == 0) {  // self-loop term on even half only
        ushort8 sv = *(const ushort8*)(base + (size_t)i * CW);
        a0 = bu2f(sv[0]); a1 = bu2f(sv[1]); a2 = bu2f(sv[2]); a3 = bu2f(sv[3]);
        a4 = bu2f(sv[4]); a5 = bu2f(sv[5]); a6 = bu2f(sv[6]); a7 = bu2f(sv[7]);
    } else {
        a0 = a1 = a2 = a3 = a4 = a5 = a6 = a7 = 0.f;
    }

    const int start = off[i];
    const int end = off[i + 1];
    const float dv = rsqrtf((float)(end - start) + 1.f);
    int k = start + h;
    for (; k + 6 < end; k += 8) {   // 4 independent loads in flight, stride-2
        int s0 = csr[k], s1 = csr[k + 2], s2 = csr[k + 4], s3 = csr[k + 6];
        ushort8 v0 = *(const ushort8*)(base + (size_t)s0 * CW);
        ushort8 v1 = *(const ushort8*)(base + (size_t)s1 * CW);
        ushort8 v2 = *(const ushort8*)(base + (size_t)s2 * CW);
        ushort8 v3 = *(const ushort8*)(base + (size_t)s3 * CW);
        a0 += (bu2f(v0[0]) + bu2f(v1[0])) + (bu2f(v2[0]) + bu2f(v3[0]));
        a1 += (bu2f(v0[1]) + bu2f(v1[1])) + (bu2f(v2[1]) + bu2f(v3[1]));
        a2 += (bu2f(v0[2]) + bu2f(v1[2])) + (bu2f(v2[2]) + bu2f(v3[2]));
        a3 += (bu2f(v0[3]) + bu2f(v1[3])) + (bu2f(v2[3]) + bu2f(v3[3]));
        a4 += (bu2f(v0[4]) + bu2f(v1[4])) + (bu2f(v2[4]) + bu2f(v3[4]));
        a5 += (bu2f(v0[5]) + bu2f(v1[5])) + (bu2f(v2[5]) + bu2f(v3[5]));
        a6 += (bu2f(v0[6]) + bu2f(v1[6])) + (bu2f(v2[6]) + bu2f(v3[6]));
        a7 += (bu2f(v0[7]) + bu2f(v1[7])) + (bu2f(v2[7]) + bu2f(v3[7]));
    }
    for (; k < end; k += 2) {
        ushort8 v0 = *(const ushort8*)(base + (size_t)csr[k] * CW);
        a0 += bu2f(v0[0]); a1 += bu2f(v0[1]); a2 += bu2f(v0[2]); a3 += bu2f(v0[3]);
        a4 += bu2f(v0[4]); a5 += bu2f(v0[5]); a6 += bu2f(v0[6]); a7 += bu2f(v0[7]);
    }
    // combine halves (adjacent lanes)
    a0 += __shfl_xor(a0, 1, 64); a1 += __shfl_xor(a1, 1, 64);
    a2 += __shfl_xor(a2, 1, 64); a3 += __shfl_xor(a3, 1, 64);
    a4 += __shfl_xor(a4, 1, 64); a5 += __shfl_xor(a5, 1, 64);
    a6 += __shfl_xor(a6, 1, 64); a7 += __shfl_xor(a7, 1, 64);
    if (h == 0) {
        const int j = c * CW + q * 8;
        ushort8 o;
        o[0] = f2bu(fmaxf(fmaf(dv, a0, bg[j + 0]), 0.f));
        o[1] = f2bu(fmaxf(fmaf(dv, a1, bg[j + 1]), 0.f));
        o[2] = f2bu(fmaxf(fmaf(dv, a2, bg[j + 2]), 0.f));
        o[3] = f2bu(fmaxf(fmaf(dv, a3, bg[j + 3]), 0.f));
        o[4] = f2bu(fmaxf(fmaf(dv, a4, bg[j + 4]), 0.f));
        o[5] = f2bu(fmaxf(fmaf(dv, a5, bg[j + 5]), 0.f));
        o[6] = f2bu(fmaxf(fmaf(dv, a6, bg[j + 6]), 0.f));
        o[7] = f2bu(fmaxf(fmaf(dv, a7, bg[j + 7]), 0.f));
        *(ushort8*)(zb + (size_t)i * ZK + j) = o;
    }
}

// ---- kernel 7: MFMA layer-1 + fused layer-2 epilogue (x·W2 via precomputed xw2) ----
__global__ __launch_bounds__(256) void k_mlp2(const unsigned short* __restrict__ zb,
                                              const unsigned short* __restrict__ Wt1,
                                              const float* __restrict__ b1,
                                              const float* __restrict__ W2,
                                              const float* __restrict__ b2,
                                              const float* __restrict__ xw2,
                                              float* __restrict__ out) {
    const int wave = threadIdx.x >> 6;
    const int lane = threadIdx.x & 63;
    const int quad = lane >> 4;
    const int l16 = lane & 15;
    const int Mbase = blockIdx.x * 64 + wave * 16;

    const unsigned short* arow = zb + (size_t)(Mbase + l16) * ZK + quad * 8;
    const unsigned short* brow = Wt1 + (size_t)l16 * ZK + quad * 8;

    f32x4 acc[6] = {};
#pragma unroll
    for (int ks = 0; ks < 4; ++ks) {
        short8 a = *(const short8*)(arow + ks * 32);
#pragma unroll
        for (int nt = 0; nt < 6; ++nt) {
            short8 bfrag = *(const short8*)(brow + (size_t)nt * 16 * ZK + ks * 32);
            acc[nt] = __builtin_amdgcn_mfma_f32_16x16x32_bf16(a, bfrag, acc[nt], 0, 0, 0);
        }
    }
    float bb[6], wa[6];
#pragma unroll
    for (int nt = 0; nt < 6; ++nt) {
        int c = nt * 16 + l16;
        bb[nt] = b1[c];
        wa[nt] = W2[c];
    }
    const float bias2 = b2[0];

#pragma unroll
    for (int reg = 0; reg < 4; ++reg) {
        const int r = Mbase + quad * 4 + reg;
        float p = 0.f;
#pragma unroll
        for (int nt = 0; nt < 6; ++nt)
            p = fmaf(fmaxf(acc[nt][reg] + bb[nt], 0.f), wa[nt], p);
#pragma unroll
        for (int m = 1; m < 16; m <<= 1) p += __shfl_xor(p, m, 64);
        if (l16 == 0 && r < NN) out[r] = fmaxf(p + xw2[r] + bias2, 0.f);
    }
}

extern "C" void kernel_launch(void* const* d_in, const int* in_sizes, int n_in,
                              void* d_out, int out_size, void* d_ws, size_t ws_size,
                              hipStream_t stream) {
    const float* x   = (const float*)d_in[0];
    const int*   ei  = (const int*)d_in[1];
    const float* tmp = (const float*)d_in[2];
    const float* Wg  = (const float*)d_in[3];
    const float* bg  = (const float*)d_in[4];
    const float* W1  = (const float*)d_in[5];
    const float* b1  = (const float*)d_in[6];
    const float* W2  = (const float*)d_in[7];
    const float* b2  = (const float*)d_in[8];
    float* out = (float*)d_out;

    char* base = (char*)d_ws;
    int* off  = (int*)base;                         // NN+1 ints
    int* bcur = off + 65536;                        // 256 ints
    unsigned short* csr = (unsigned short*)(bcur + 512);   // NE ushort = 1.6 MB; all < 4 MiB
    unsigned short* Wt  = (unsigned short*)(base + ((size_t)4 << 20));  // NF*HH bf16
    unsigned short* Wt1 = Wt + NF * HH;             // HH*ZK bf16
    unsigned short* hp_c = Wt1 + HH * ZK;           // NN*HH bf16 (chunked) = 9.6 MB
    unsigned short* zb = hp_c + (size_t)NN * HH;    // NPAD*ZK bf16 = 12.8 MB
    float* xw2 = (float*)(zb + (size_t)NPAD * ZK);  // NPAD floats = 200 KB
    int* temp = (int*)zb;   // 196*5120 ints = 4.01 MB, aliases zb (consumed before zb written)

    k_init <<<1, 256, 0, stream>>>(bcur, off);
    k_fillA<<<(NE + EPB - 1) / EPB, 256, 0, stream>>>(ei, bcur, temp);
    k_fillB<<<NBK, 256, 0, stream>>>(temp, bcur, csr, off);
    k_prep <<<WBLK + W1BLK + ZTBLK + ZPBLK, 256, 0, stream>>>(Wg, W1, tmp, Wt, Wt1, zb);
    k_gemm <<<NPAD / 64, 256, 0, stream>>>(x, Wt, off, W2, hp_c, xw2);
    k_agg  <<<AGGB, 256, 0, stream>>>(hp_c, off, csr, bg, zb);
    k_mlp2 <<<NPAD / 64, 256, 0, stream>>>(zb, Wt1, b1, W2, b2, xw2, out);
}